// Round 1
// baseline (1540.496 us; speedup 1.0000x reference)
//
#include <hip/hip_runtime.h>
#include <cstddef>
#include <cstdint>

// Problem constants
#define BATCH 2
#define SEQ   2048
#define DM    1024   // d_model
#define ED    2048   // d_inner
#define NS    16     // d_state
#define DR    64     // dt_rank
#define NROWS (BATCH*SEQ)  // 4096

// workspace layout (float offsets). Order matters: scan prefetches one row
// past the end of dt/u/dbc; each overrun lands in the next (valid) region.
#define OFF_XR   ((size_t)0)          // 16,777,216 floats (B,L,2*ED)
#define OFF_U    ((size_t)16777216)   //  8,388,608 floats (B,L,ED); reused for gated y
#define OFF_DT   ((size_t)25165824)   //  8,388,608 floats (B,L,ED); scan writes y_ssm in-place
#define OFF_DBC  ((size_t)33554432)   //    393,216 floats (B,L,96)
#define OFF_PART ((size_t)33947648)   //  3,145,728 floats (8 split-K partials)
// total: 37,093,376 floats = 148.4 MB

__device__ __forceinline__ float silu_f(float x) { return x / (1.f + __expf(-x)); }

// ---------------------------------------------------------------------------
// Classic 128x128 register-blocked SGEMM, TK=8, 256 threads, 8x8 microtile.
// A: MxK row-major with row stride lda. Bm: KxN row-major. C: MxN (ldc=N).
// EPI==1: C = softplus(acc + bias[n]) (for dt_proj).
// Requires M%128==0, N%128==0, K%8==0 (true for all uses here).
// ---------------------------------------------------------------------------
template<int EPI>
__global__ __launch_bounds__(256)
void sgemm128(const float* __restrict__ A, int lda,
              const float* __restrict__ Bm, const float* __restrict__ bias,
              float* __restrict__ C, int N, int K) {
  __shared__ float As[8][128];   // [k][m]
  __shared__ float Bs[8][128];   // [k][n]
  const int tid  = threadIdx.x;
  const int m0   = blockIdx.y * 128;
  const int n0   = blockIdx.x * 128;
  const int tx   = tid & 15;       // n-subtile
  const int ty   = tid >> 4;       // m-subtile
  const int arow = tid >> 1;       // 0..127
  const int acol = (tid & 1) * 4;  // 0 or 4
  const int brow = tid >> 5;       // 0..7
  const int bcol = (tid & 31) * 4; // 0..124

  const float* Ap = A + (size_t)(m0 + arow) * lda + acol;
  const float* Bp = Bm + (size_t)brow * N + n0 + bcol;

  float acc[8][8];
  #pragma unroll
  for (int i = 0; i < 8; ++i)
    #pragma unroll
    for (int j = 0; j < 8; ++j) acc[i][j] = 0.f;

  for (int k0 = 0; k0 < K; k0 += 8) {
    const float4 av = *(const float4*)(Ap + k0);
    const float4 bv = *(const float4*)(Bp + (size_t)k0 * N);
    __syncthreads();
    As[acol + 0][arow] = av.x;   // 2-way LDS bank alias: free on CDNA4
    As[acol + 1][arow] = av.y;
    As[acol + 2][arow] = av.z;
    As[acol + 3][arow] = av.w;
    *(float4*)&Bs[brow][bcol] = bv;
    __syncthreads();
    #pragma unroll
    for (int k = 0; k < 8; ++k) {
      float a[8], b[8];
      *(float4*)(a)     = *(const float4*)&As[k][ty * 8];
      *(float4*)(a + 4) = *(const float4*)&As[k][ty * 8 + 4];
      *(float4*)(b)     = *(const float4*)&Bs[k][tx * 8];
      *(float4*)(b + 4) = *(const float4*)&Bs[k][tx * 8 + 4];
      #pragma unroll
      for (int i = 0; i < 8; ++i)
        #pragma unroll
        for (int j = 0; j < 8; ++j)
          acc[i][j] = fmaf(a[i], b[j], acc[i][j]);
    }
  }

  #pragma unroll
  for (int i = 0; i < 8; ++i) {
    float* Cp = C + (size_t)(m0 + ty * 8 + i) * N + n0 + tx * 8;
    #pragma unroll
    for (int j = 0; j < 8; ++j) {
      float v = acc[i][j];
      if (EPI == 1) {
        v += bias[n0 + tx * 8 + j];
        // numerically stable softplus
        v = fmaxf(v, 0.f) + log1pf(__expf(-fabsf(v)));
      }
      Cp[j] = v;
    }
  }
}

// ---------------------------------------------------------------------------
// Causal depthwise conv (width 4, left pad 3) + bias + silu.
// xb = left half (cols 0..ED-1) of xr rows of width 2*ED.
// ---------------------------------------------------------------------------
__global__ __launch_bounds__(256)
void conv_silu_kernel(const float* __restrict__ xr, const float* __restrict__ w,
                      const float* __restrict__ cb, float* __restrict__ u) {
  const int idx = blockIdx.x * 256 + threadIdx.x;   // (b*SEQ+t)*ED + d
  const int d = idx & (ED - 1);
  const int t = (idx >> 11) & (SEQ - 1);
  const float4 wv = ((const float4*)w)[d];          // conv_w[d][0][0..3]
  const float* base = xr + (size_t)(idx >> 11) * (2 * ED) + d;
  float acc = cb[d];
  acc = fmaf(wv.w, base[0], acc);
  if (t >= 1) acc = fmaf(wv.z, base[-(2 * ED)], acc);
  if (t >= 2) acc = fmaf(wv.y, base[-2 * (2 * ED)], acc);
  if (t >= 3) acc = fmaf(wv.x, base[-3 * (2 * ED)], acc);
  u[idx] = silu_f(acc);
}

// ---------------------------------------------------------------------------
// x_proj: dbc_partial[s] = u[:, sK:(s+1)K] @ Wx[sK:(s+1)K, :]   (N=96, split-K=8)
// block: 64 rows x 96 cols, 256 threads, 4x6 microtile, K-chunk 256.
// ---------------------------------------------------------------------------
__global__ __launch_bounds__(256)
void xproj_kernel(const float* __restrict__ U, const float* __restrict__ W,
                  float* __restrict__ part) {
  __shared__ float Us[32][65];
  __shared__ float Ws[32][96];
  const int tid = threadIdx.x;
  const int m0 = blockIdx.x * 64;
  const int ks = blockIdx.y * 256;
  const int tx = tid & 15;   // n = tx*6
  const int ty = tid >> 4;   // m = ty*4
  const int lm = tid >> 2;        // 0..63
  const int lk = (tid & 3) * 8;   // 0,8,16,24

  float acc[4][6];
  #pragma unroll
  for (int i = 0; i < 4; ++i)
    #pragma unroll
    for (int j = 0; j < 6; ++j) acc[i][j] = 0.f;

  for (int k0 = ks; k0 < ks + 256; k0 += 32) {
    __syncthreads();
    const float* up = U + (size_t)(m0 + lm) * ED + k0 + lk;
    const float4 u0 = *(const float4*)(up);
    const float4 u1 = *(const float4*)(up + 4);
    Us[lk + 0][lm] = u0.x; Us[lk + 1][lm] = u0.y;
    Us[lk + 2][lm] = u0.z; Us[lk + 3][lm] = u0.w;
    Us[lk + 4][lm] = u1.x; Us[lk + 5][lm] = u1.y;
    Us[lk + 6][lm] = u1.z; Us[lk + 7][lm] = u1.w;
    for (int i = tid; i < 32 * 96; i += 256) {
      const int kk = i / 96, nn = i - kk * 96;
      Ws[kk][nn] = W[(size_t)(k0 + kk) * 96 + nn];
    }
    __syncthreads();
    #pragma unroll
    for (int k = 0; k < 32; ++k) {
      float a[4], wv[6];
      #pragma unroll
      for (int i = 0; i < 4; ++i) a[i] = Us[k][ty * 4 + i];
      #pragma unroll
      for (int j = 0; j < 6; ++j) wv[j] = Ws[k][tx * 6 + j];
      #pragma unroll
      for (int i = 0; i < 4; ++i)
        #pragma unroll
        for (int j = 0; j < 6; ++j)
          acc[i][j] = fmaf(a[i], wv[j], acc[i][j]);
    }
  }
  float* pp = part + (size_t)blockIdx.y * NROWS * 96;
  #pragma unroll
  for (int i = 0; i < 4; ++i)
    #pragma unroll
    for (int j = 0; j < 6; ++j)
      pp[(size_t)(m0 + ty * 4 + i) * 96 + tx * 6 + j] = acc[i][j];
}

__global__ __launch_bounds__(256)
void xproj_reduce(const float* __restrict__ part, float* __restrict__ dbc) {
  const int idx = blockIdx.x * 256 + threadIdx.x;  // < NROWS*96
  float s = 0.f;
  #pragma unroll
  for (int r = 0; r < 8; ++r) s += part[(size_t)r * NROWS * 96 + idx];
  dbc[idx] = s;
}

// ---------------------------------------------------------------------------
// Selective scan: 16 lanes per (b,d) channel, one lane per state n.
// h_n <- h_n * exp(dt*A_dn) + dt*u*B_n;  y = sum_n h_n*C_n + D*u.
// Writes y_ssm in-place over dt (same (b,t,d) element, read-before-write).
// Prefetch of t+1 reads one row past the end on the last iter — lands in the
// next workspace region (valid memory, value unused).
// ---------------------------------------------------------------------------
__global__ __launch_bounds__(256)
void scan_kernel(const float* __restrict__ dt, const float* __restrict__ u,
                 const float* __restrict__ dbc, const float* __restrict__ A_log,
                 const float* __restrict__ Dp, float* __restrict__ y) {
  const int lane = threadIdx.x & 15;                 // state index n
  const int c = blockIdx.x * 16 + (threadIdx.x >> 4); // channel in [0, B*ED)
  const int b = c >> 11;
  const int d = c & (ED - 1);
  const float Adn = -__expf(A_log[d * NS + lane]);
  const float Dd = Dp[d];
  const float* dtp = dt + (size_t)b * SEQ * ED + d;
  const float* up  = u  + (size_t)b * SEQ * ED + d;
  const float* bcp = dbc + (size_t)b * SEQ * 96 + DR;
  float* yp = y + (size_t)b * SEQ * ED + d;

  float h = 0.f;
  float dti = dtp[0], ui = up[0], Bi = bcp[lane], Ci = bcp[NS + lane];
  for (int t = 0; t < SEQ; ++t) {
    const size_t o = (size_t)(t + 1) * ED;
    const float dtn = dtp[o];
    const float un  = up[o];
    const float Bn  = bcp[(t + 1) * 96 + lane];
    const float Cn  = bcp[(t + 1) * 96 + NS + lane];

    const float dA = __expf(dti * Adn);
    h = fmaf(h, dA, dti * ui * Bi);
    float yv = h * Ci;
    yv += __shfl_xor(yv, 1);
    yv += __shfl_xor(yv, 2);
    yv += __shfl_xor(yv, 4);
    yv += __shfl_xor(yv, 8);
    if (lane == 0) yp[(size_t)t * ED] = fmaf(Dd, ui, yv);

    dti = dtn; ui = un; Bi = Bn; Ci = Cn;
  }
}

// y = y_ssm * silu(res);  res = right half of xr rows.
__global__ __launch_bounds__(256)
void gate_kernel(const float* __restrict__ yssm, const float* __restrict__ xr,
                 float* __restrict__ y) {
  const int idx = blockIdx.x * 256 + threadIdx.x;
  const int d = idx & (ED - 1);
  const size_t row = (size_t)(idx >> 11);
  const float r = xr[row * (2 * ED) + ED + d];
  y[idx] = yssm[idx] * silu_f(r);
}

extern "C" void kernel_launch(void* const* d_in, const int* in_sizes, int n_in,
                              void* d_out, int out_size, void* d_ws, size_t ws_size,
                              hipStream_t stream) {
  (void)in_sizes; (void)n_in; (void)out_size; (void)ws_size;
  const float* x     = (const float*)d_in[0];
  const float* Win   = (const float*)d_in[1];
  const float* convw = (const float*)d_in[2];
  const float* convb = (const float*)d_in[3];
  const float* Wx    = (const float*)d_in[4];
  const float* Wdt   = (const float*)d_in[5];
  const float* bdt   = (const float*)d_in[6];
  const float* Alog  = (const float*)d_in[7];
  const float* Dp    = (const float*)d_in[8];
  const float* Wout  = (const float*)d_in[9];

  float* ws   = (float*)d_ws;
  float* xr   = ws + OFF_XR;
  float* u    = ws + OFF_U;
  float* dt   = ws + OFF_DT;
  float* dbc  = ws + OFF_DBC;
  float* part = ws + OFF_PART;
  float* out  = (float*)d_out;

  // 1) xr = x @ in_proj_w      (4096x1024)@(1024x4096)
  sgemm128<0><<<dim3((2 * ED) / 128, NROWS / 128), 256, 0, stream>>>(
      x, DM, Win, nullptr, xr, 2 * ED, DM);
  // 2) u = silu(causal_dwconv(xb) + conv_b)
  conv_silu_kernel<<<(NROWS * ED) / 256, 256, 0, stream>>>(xr, convw, convb, u);
  // 3) dbc = u @ x_proj_w      (split-K=8 + reduce)
  xproj_kernel<<<dim3(NROWS / 64, 8), 256, 0, stream>>>(u, Wx, part);
  xproj_reduce<<<(NROWS * 96) / 256, 256, 0, stream>>>(part, dbc);
  // 4) dt = softplus(dbc[:, :64] @ dt_proj_w + dt_proj_b)
  sgemm128<1><<<dim3(ED / 128, NROWS / 128), 256, 0, stream>>>(
      dbc, 96, Wdt, bdt, dt, ED, DR);
  // 5) selective scan -> y_ssm (in-place over dt)
  scan_kernel<<<(BATCH * ED) / 16, 256, 0, stream>>>(dt, u, dbc, Alog, Dp, dt);
  // 6) y = y_ssm * silu(res)   (into u buffer; u is dead after the scan)
  gate_kernel<<<(NROWS * ED) / 256, 256, 0, stream>>>(dt, xr, u);
  // 7) out = y @ out_proj_w    (4096x2048)@(2048x1024)
  sgemm128<0><<<dim3(DM / 128, NROWS / 128), 256, 0, stream>>>(
      u, ED, Wout, nullptr, out, DM, ED);
}

// Round 2
// 1211.631 us; speedup vs baseline: 1.2714x; 1.2714x over previous
//
#include <hip/hip_runtime.h>
#include <cstddef>
#include <cstdint>

// Problem constants
#define BATCH 2
#define SEQ   2048
#define DM    1024   // d_model
#define ED    2048   // d_inner
#define NS    16     // d_state
#define DR    64     // dt_rank
#define NROWS (BATCH*SEQ)  // 4096

// Chunked-scan parameters: SEQ = NCHUNK * CLEN
#define NCHUNK 16
#define CLEN   128
#define CSTATES (BATCH*ED*NS)   // 65536 independent recurrences

// workspace layout (float offsets)
#define OFF_XR   ((size_t)0)          // 16,777,216 floats (B,L,2*ED)
#define OFF_U    ((size_t)16777216)   //  8,388,608 floats (B,L,ED); reused for gated y
#define OFF_DT   ((size_t)25165824)   //  8,388,608 floats (B,L,ED); scan writes y_ssm in-place
#define OFF_DBC  ((size_t)33554432)   //    393,216 floats (B,L,96)
#define OFF_PART ((size_t)33947648)   //  3,145,728 floats (8 split-K partials; reused as P/S)
// total: 37,093,376 floats = 148.4 MB
// P/S chunk summaries: P = part[0 .. 1,048,576), S = part[1,048,576 .. 2,097,152)

__device__ __forceinline__ float silu_f(float x) { return x / (1.f + __expf(-x)); }

// ---------------------------------------------------------------------------
// Classic 128x128 register-blocked SGEMM, TK=8, 256 threads, 8x8 microtile.
// A: MxK row-major with row stride lda. Bm: KxN row-major. C: MxN (ldc=N).
// EPI==1: C = softplus(acc + bias[n]) (for dt_proj).
// ---------------------------------------------------------------------------
template<int EPI>
__global__ __launch_bounds__(256)
void sgemm128(const float* __restrict__ A, int lda,
              const float* __restrict__ Bm, const float* __restrict__ bias,
              float* __restrict__ C, int N, int K) {
  __shared__ float As[8][128];   // [k][m]
  __shared__ float Bs[8][128];   // [k][n]
  const int tid  = threadIdx.x;
  const int m0   = blockIdx.y * 128;
  const int n0   = blockIdx.x * 128;
  const int tx   = tid & 15;       // n-subtile
  const int ty   = tid >> 4;       // m-subtile
  const int arow = tid >> 1;       // 0..127
  const int acol = (tid & 1) * 4;  // 0 or 4
  const int brow = tid >> 5;       // 0..7
  const int bcol = (tid & 31) * 4; // 0..124

  const float* Ap = A + (size_t)(m0 + arow) * lda + acol;
  const float* Bp = Bm + (size_t)brow * N + n0 + bcol;

  float acc[8][8];
  #pragma unroll
  for (int i = 0; i < 8; ++i)
    #pragma unroll
    for (int j = 0; j < 8; ++j) acc[i][j] = 0.f;

  for (int k0 = 0; k0 < K; k0 += 8) {
    const float4 av = *(const float4*)(Ap + k0);
    const float4 bv = *(const float4*)(Bp + (size_t)k0 * N);
    __syncthreads();
    As[acol + 0][arow] = av.x;   // 2-way LDS bank alias: free on CDNA4
    As[acol + 1][arow] = av.y;
    As[acol + 2][arow] = av.z;
    As[acol + 3][arow] = av.w;
    *(float4*)&Bs[brow][bcol] = bv;
    __syncthreads();
    #pragma unroll
    for (int k = 0; k < 8; ++k) {
      float a[8], b[8];
      *(float4*)(a)     = *(const float4*)&As[k][ty * 8];
      *(float4*)(a + 4) = *(const float4*)&As[k][ty * 8 + 4];
      *(float4*)(b)     = *(const float4*)&Bs[k][tx * 8];
      *(float4*)(b + 4) = *(const float4*)&Bs[k][tx * 8 + 4];
      #pragma unroll
      for (int i = 0; i < 8; ++i)
        #pragma unroll
        for (int j = 0; j < 8; ++j)
          acc[i][j] = fmaf(a[i], b[j], acc[i][j]);
    }
  }

  #pragma unroll
  for (int i = 0; i < 8; ++i) {
    float* Cp = C + (size_t)(m0 + ty * 8 + i) * N + n0 + tx * 8;
    #pragma unroll
    for (int j = 0; j < 8; ++j) {
      float v = acc[i][j];
      if (EPI == 1) {
        v += bias[n0 + tx * 8 + j];
        v = fmaxf(v, 0.f) + log1pf(__expf(-fabsf(v)));  // stable softplus
      }
      Cp[j] = v;
    }
  }
}

// ---------------------------------------------------------------------------
// Causal depthwise conv (width 4, left pad 3) + bias + silu.
// ---------------------------------------------------------------------------
__global__ __launch_bounds__(256)
void conv_silu_kernel(const float* __restrict__ xr, const float* __restrict__ w,
                      const float* __restrict__ cb, float* __restrict__ u) {
  const int idx = blockIdx.x * 256 + threadIdx.x;   // (b*SEQ+t)*ED + d
  const int d = idx & (ED - 1);
  const int t = (idx >> 11) & (SEQ - 1);
  const float4 wv = ((const float4*)w)[d];          // conv_w[d][0][0..3]
  const float* base = xr + (size_t)(idx >> 11) * (2 * ED) + d;
  float acc = cb[d];
  acc = fmaf(wv.w, base[0], acc);
  if (t >= 1) acc = fmaf(wv.z, base[-(2 * ED)], acc);
  if (t >= 2) acc = fmaf(wv.y, base[-2 * (2 * ED)], acc);
  if (t >= 3) acc = fmaf(wv.x, base[-3 * (2 * ED)], acc);
  u[idx] = silu_f(acc);
}

// ---------------------------------------------------------------------------
// x_proj: split-K=8 partials then reduce (N=96).
// ---------------------------------------------------------------------------
__global__ __launch_bounds__(256)
void xproj_kernel(const float* __restrict__ U, const float* __restrict__ W,
                  float* __restrict__ part) {
  __shared__ float Us[32][65];
  __shared__ float Ws[32][96];
  const int tid = threadIdx.x;
  const int m0 = blockIdx.x * 64;
  const int ks = blockIdx.y * 256;
  const int tx = tid & 15;   // n = tx*6
  const int ty = tid >> 4;   // m = ty*4
  const int lm = tid >> 2;        // 0..63
  const int lk = (tid & 3) * 8;   // 0,8,16,24

  float acc[4][6];
  #pragma unroll
  for (int i = 0; i < 4; ++i)
    #pragma unroll
    for (int j = 0; j < 6; ++j) acc[i][j] = 0.f;

  for (int k0 = ks; k0 < ks + 256; k0 += 32) {
    __syncthreads();
    const float* up = U + (size_t)(m0 + lm) * ED + k0 + lk;
    const float4 u0 = *(const float4*)(up);
    const float4 u1 = *(const float4*)(up + 4);
    Us[lk + 0][lm] = u0.x; Us[lk + 1][lm] = u0.y;
    Us[lk + 2][lm] = u0.z; Us[lk + 3][lm] = u0.w;
    Us[lk + 4][lm] = u1.x; Us[lk + 5][lm] = u1.y;
    Us[lk + 6][lm] = u1.z; Us[lk + 7][lm] = u1.w;
    for (int i = tid; i < 32 * 96; i += 256) {
      const int kk = i / 96, nn = i - kk * 96;
      Ws[kk][nn] = W[(size_t)(k0 + kk) * 96 + nn];
    }
    __syncthreads();
    #pragma unroll
    for (int k = 0; k < 32; ++k) {
      float a[4], wv[6];
      #pragma unroll
      for (int i = 0; i < 4; ++i) a[i] = Us[k][ty * 4 + i];
      #pragma unroll
      for (int j = 0; j < 6; ++j) wv[j] = Ws[k][tx * 6 + j];
      #pragma unroll
      for (int i = 0; i < 4; ++i)
        #pragma unroll
        for (int j = 0; j < 6; ++j)
          acc[i][j] = fmaf(a[i], wv[j], acc[i][j]);
    }
  }
  float* pp = part + (size_t)blockIdx.y * NROWS * 96;
  #pragma unroll
  for (int i = 0; i < 4; ++i)
    #pragma unroll
    for (int j = 0; j < 6; ++j)
      pp[(size_t)(m0 + ty * 4 + i) * 96 + tx * 6 + j] = acc[i][j];
}

__global__ __launch_bounds__(256)
void xproj_reduce(const float* __restrict__ part, float* __restrict__ dbc) {
  const int idx = blockIdx.x * 256 + threadIdx.x;  // < NROWS*96
  float s = 0.f;
  #pragma unroll
  for (int r = 0; r < 8; ++r) s += part[(size_t)r * NROWS * 96 + idx];
  dbc[idx] = s;
}

// ---------------------------------------------------------------------------
// Chunked selective scan.
// Recurrence per (b,d,n): h <- h*exp(dt*A) + dt*u*B;  y = sum_n h*C + D*u.
// Thread tau: n = tau&15, bd = (tau>>4)&4095, g = tau>>16 (chunk).
// Lanes 0..15 of a 16-lane group share (b,d) -> dt/u loads broadcast,
// shfl_xor {1,2,4,8} reduces over the 16 states.
// ---------------------------------------------------------------------------
__global__ __launch_bounds__(256)
void scan_chunk_summary(const float* __restrict__ dt, const float* __restrict__ u,
                        const float* __restrict__ dbc, const float* __restrict__ A_log,
                        float* __restrict__ Pbuf, float* __restrict__ Sbuf) {
  const unsigned tau = blockIdx.x * 256 + threadIdx.x;
  const int n  = tau & 15;
  const int bd = (tau >> 4) & (BATCH * ED - 1);
  const int g  = tau >> 16;
  const int b = bd >> 11, d = bd & (ED - 1);
  const float Adn = -__expf(A_log[d * NS + n]);
  const size_t row0 = (size_t)b * SEQ + (size_t)g * CLEN;
  const float* dtp = dt + row0 * ED + d;
  const float* up  = u  + row0 * ED + d;
  const float* Bp  = dbc + row0 * 96 + DR + n;

  float P = 1.f, S = 0.f;
  for (int t = 0; t < CLEN; ++t) {
    const float dti = dtp[(size_t)t * ED];
    const float ui  = up[(size_t)t * ED];
    const float Bi  = Bp[(size_t)t * 96];
    const float a = __expf(dti * Adn);
    S = fmaf(S, a, dti * ui * Bi);
    P *= a;
  }
  const unsigned c = tau & (CSTATES - 1);
  Pbuf[(size_t)g * CSTATES + c] = P;
  Sbuf[(size_t)g * CSTATES + c] = S;
}

// Sequential composition over the 16 chunk summaries; writes each chunk's
// ENTRY state h0 over Pbuf (read-before-write, same thread).
__global__ __launch_bounds__(256)
void scan_chunk_compose(float* __restrict__ Pbuf, const float* __restrict__ Sbuf) {
  const unsigned c = blockIdx.x * 256 + threadIdx.x;  // < CSTATES
  float h = 0.f;
  #pragma unroll
  for (int g = 0; g < NCHUNK; ++g) {
    const size_t idx = (size_t)g * CSTATES + c;
    const float p = Pbuf[idx], s = Sbuf[idx];
    Pbuf[idx] = h;
    h = fmaf(p, h, s);
  }
}

// Final pass: rerun recurrence from h0, emit y (in-place over dt).
__global__ __launch_bounds__(256)
void scan_chunk_apply(const float* __restrict__ dt, const float* __restrict__ u,
                      const float* __restrict__ dbc, const float* __restrict__ A_log,
                      const float* __restrict__ Dp, const float* __restrict__ Pbuf,
                      float* __restrict__ y) {
  const unsigned tau = blockIdx.x * 256 + threadIdx.x;
  const int n  = tau & 15;
  const int bd = (tau >> 4) & (BATCH * ED - 1);
  const int g  = tau >> 16;
  const int b = bd >> 11, d = bd & (ED - 1);
  const float Adn = -__expf(A_log[d * NS + n]);
  const float Dd = Dp[d];
  const size_t row0 = (size_t)b * SEQ + (size_t)g * CLEN;
  const float* dtp = dt + row0 * ED + d;
  const float* up  = u  + row0 * ED + d;
  const float* Bp  = dbc + row0 * 96 + DR + n;
  const float* Cp  = dbc + row0 * 96 + DR + NS + n;
  float* yp = y + row0 * ED + d;

  const unsigned c = tau & (CSTATES - 1);
  float h = Pbuf[(size_t)g * CSTATES + c];

  for (int t = 0; t < CLEN; ++t) {
    const float dti = dtp[(size_t)t * ED];
    const float ui  = up[(size_t)t * ED];
    const float Bi  = Bp[(size_t)t * 96];
    const float Ci  = Cp[(size_t)t * 96];
    const float a = __expf(dti * Adn);
    h = fmaf(h, a, dti * ui * Bi);
    float yv = h * Ci;
    yv += __shfl_xor(yv, 1);
    yv += __shfl_xor(yv, 2);
    yv += __shfl_xor(yv, 4);
    yv += __shfl_xor(yv, 8);
    if (n == 0) yp[(size_t)t * ED] = fmaf(Dd, ui, yv);
  }
}

// y = y_ssm * silu(res);  res = right half of xr rows.
__global__ __launch_bounds__(256)
void gate_kernel(const float* __restrict__ yssm, const float* __restrict__ xr,
                 float* __restrict__ y) {
  const int idx = blockIdx.x * 256 + threadIdx.x;
  const int d = idx & (ED - 1);
  const size_t row = (size_t)(idx >> 11);
  const float r = xr[row * (2 * ED) + ED + d];
  y[idx] = yssm[idx] * silu_f(r);
}

extern "C" void kernel_launch(void* const* d_in, const int* in_sizes, int n_in,
                              void* d_out, int out_size, void* d_ws, size_t ws_size,
                              hipStream_t stream) {
  (void)in_sizes; (void)n_in; (void)out_size; (void)ws_size;
  const float* x     = (const float*)d_in[0];
  const float* Win   = (const float*)d_in[1];
  const float* convw = (const float*)d_in[2];
  const float* convb = (const float*)d_in[3];
  const float* Wx    = (const float*)d_in[4];
  const float* Wdt   = (const float*)d_in[5];
  const float* bdt   = (const float*)d_in[6];
  const float* Alog  = (const float*)d_in[7];
  const float* Dp    = (const float*)d_in[8];
  const float* Wout  = (const float*)d_in[9];

  float* ws   = (float*)d_ws;
  float* xr   = ws + OFF_XR;
  float* u    = ws + OFF_U;
  float* dt   = ws + OFF_DT;
  float* dbc  = ws + OFF_DBC;
  float* part = ws + OFF_PART;
  float* Pbuf = part;                                  // 1,048,576 floats
  float* Sbuf = part + (size_t)NCHUNK * CSTATES;       // 1,048,576 floats
  float* out  = (float*)d_out;

  // 1) xr = x @ in_proj_w      (4096x1024)@(1024x4096)
  sgemm128<0><<<dim3((2 * ED) / 128, NROWS / 128), 256, 0, stream>>>(
      x, DM, Win, nullptr, xr, 2 * ED, DM);
  // 2) u = silu(causal_dwconv(xb) + conv_b)
  conv_silu_kernel<<<(NROWS * ED) / 256, 256, 0, stream>>>(xr, convw, convb, u);
  // 3) dbc = u @ x_proj_w      (split-K=8 + reduce)
  xproj_kernel<<<dim3(NROWS / 64, 8), 256, 0, stream>>>(u, Wx, part);
  xproj_reduce<<<(NROWS * 96) / 256, 256, 0, stream>>>(part, dbc);
  // 4) dt = softplus(dbc[:, :64] @ dt_proj_w + dt_proj_b)
  sgemm128<1><<<dim3(ED / 128, NROWS / 128), 256, 0, stream>>>(
      dbc, 96, Wdt, bdt, dt, ED, DR);
  // 5) chunked selective scan -> y_ssm (in-place over dt)
  scan_chunk_summary<<<(CSTATES * NCHUNK) / 256, 256, 0, stream>>>(
      dt, u, dbc, Alog, Pbuf, Sbuf);
  scan_chunk_compose<<<CSTATES / 256, 256, 0, stream>>>(Pbuf, Sbuf);
  scan_chunk_apply<<<(CSTATES * NCHUNK) / 256, 256, 0, stream>>>(
      dt, u, dbc, Alog, Dp, Pbuf, dt);
  // 6) y = y_ssm * silu(res)   (into u buffer; u is dead after the scan)
  gate_kernel<<<(NROWS * ED) / 256, 256, 0, stream>>>(dt, xr, u);
  // 7) out = y @ out_proj_w    (4096x2048)@(2048x1024)
  sgemm128<0><<<dim3(DM / 128, NROWS / 128), 256, 0, stream>>>(
      u, ED, Wout, nullptr, out, DM, ED);
}

// Round 3
// 507.209 us; speedup vs baseline: 3.0372x; 2.3888x over previous
//
#include <hip/hip_runtime.h>
#include <cstddef>
#include <cstdint>

// Problem constants
#define BATCH 2
#define SEQ   2048
#define DM    1024   // d_model
#define ED    2048   // d_inner
#define NS    16     // d_state
#define DR    64     // dt_rank
#define NROWS (BATCH*SEQ)  // 4096

// Chunked-scan parameters: SEQ = NCHUNK * CLEN
#define NCHUNK 16
#define CLEN   128
#define CSTATES (BATCH*ED*NS)   // 65536 independent recurrences

// workspace layout (float offsets)
#define OFF_XR   ((size_t)0)          // 16,777,216 floats (B,L,2*ED)
#define OFF_U    ((size_t)16777216)   //  8,388,608 floats (B,L,ED); reused as fp16 y_h
#define OFF_DT   ((size_t)25165824)   //  8,388,608 floats; first 16MB doubles as x_h+Wint (dead before dt written)
#define OFF_DBC  ((size_t)33554432)   //    393,216 floats (B,L,96)
#define OFF_PART ((size_t)33947648)   //  3,145,728 floats (split-K partials; reused as P/S, then Woutt)
// total: 37,093,376 floats = 148.4 MB (unchanged from round 2)

typedef _Float16 half8 __attribute__((ext_vector_type(8)));
typedef _Float16 half4 __attribute__((ext_vector_type(4)));
typedef float    floatx4 __attribute__((ext_vector_type(4)));

__device__ __forceinline__ float silu_f(float x) { return x / (1.f + __expf(-x)); }

__device__ __forceinline__ void gload_lds16(const _Float16* g, _Float16* l) {
  __builtin_amdgcn_global_load_lds(
      (const __attribute__((address_space(1))) void*)g,
      (__attribute__((address_space(3))) void*)l, 16, 0, 0);
}

// ---------------------------------------------------------------------------
// fp16 MFMA GEMM (m97 recipe): C(MxN fp32) = A(MxK fp16 row-major) @ Bt^T,
// Bt is B transposed: Bt[n][k] fp16 row-major (ldb = K). BM=128, BK=32.
// 256 threads = 4 waves in WGM x WGN grid; wave computes FMx FN 16x16 tiles
// via v_mfma_f32_16x16x32_f16.
// LDS layout: [row][chunk] of 8-half (16B) chunks with XOR swizzle
// c_l = c_g ^ ((row>>1)&3): keeps global_load_lds lane-contiguity AND makes
// frag ds_read_b128 hit each 4-bank group exactly 2x (2-way = free on CDNA4).
// ---------------------------------------------------------------------------
template<int BN, int WGM, int WGN>
__global__ __launch_bounds__(256)
void hgemm(const _Float16* __restrict__ A, int lda,
           const _Float16* __restrict__ Bt, int ldb,
           float* __restrict__ C, int N, int K) {
  constexpr int BM = 128;
  constexpr int FM = BM / 16 / WGM;
  constexpr int FN = BN / 16 / WGN;
  __shared__ _Float16 sA[BM * 32];
  __shared__ _Float16 sB[BN * 32];
  const int tid = threadIdx.x;
  const int ln  = tid & 63;
  const int wid = tid >> 6;
  const int wm  = wid % WGM;
  const int wn  = wid / WGM;
  const int m0  = blockIdx.y * BM;
  const int n0  = blockIdx.x * BN;
  const int l15 = ln & 15;
  const int q   = ln >> 4;

  floatx4 acc[FM][FN];
  #pragma unroll
  for (int i = 0; i < FM; ++i)
    #pragma unroll
    for (int j = 0; j < FN; ++j)
      acc[i][j] = floatx4{0.f, 0.f, 0.f, 0.f};

  for (int k0 = 0; k0 < K; k0 += 32) {
    __syncthreads();
    // stage A tile: BM rows x 32k halves = BM*4 16B slots, lane-ordered
    #pragma unroll
    for (int s = 0; s < (BM * 4) / 256; ++s) {
      const int i = s * 256 + tid;
      const int m = i >> 2;
      const int cg = (i & 3) ^ ((m >> 1) & 3);
      gload_lds16(A + (size_t)(m0 + m) * lda + k0 + cg * 8, sA + i * 8);
    }
    // stage Bt tile: BN rows x 32k
    #pragma unroll
    for (int s = 0; s < (BN * 4) / 256; ++s) {
      const int i = s * 256 + tid;
      const int n = i >> 2;
      const int cg = (i & 3) ^ ((n >> 1) & 3);
      gload_lds16(Bt + (size_t)(n0 + n) * ldb + k0 + cg * 8, sB + i * 8);
    }
    __syncthreads();

    half8 af[FM], bf[FN];
    #pragma unroll
    for (int fm = 0; fm < FM; ++fm) {
      const int mr = wm * FM * 16 + fm * 16 + l15;
      const int cl = q ^ ((mr >> 1) & 3);
      af[fm] = *(const half8*)(sA + mr * 32 + cl * 8);
    }
    #pragma unroll
    for (int fn = 0; fn < FN; ++fn) {
      const int nr = wn * FN * 16 + fn * 16 + l15;
      const int cl = q ^ ((nr >> 1) & 3);
      bf[fn] = *(const half8*)(sB + nr * 32 + cl * 8);
    }
    #pragma unroll
    for (int fm = 0; fm < FM; ++fm)
      #pragma unroll
      for (int fn = 0; fn < FN; ++fn)
        acc[fm][fn] = __builtin_amdgcn_mfma_f32_16x16x32_f16(
            af[fm], bf[fn], acc[fm][fn], 0, 0, 0);
  }

  // epilogue: C/D layout col=lane&15, row=(lane>>4)*4+reg (m89/m91 verified)
  #pragma unroll
  for (int fm = 0; fm < FM; ++fm) {
    #pragma unroll
    for (int fn = 0; fn < FN; ++fn) {
      const int col = n0 + wn * FN * 16 + fn * 16 + l15;
      #pragma unroll
      for (int r = 0; r < 4; ++r) {
        const int row = m0 + wm * FM * 16 + fm * 16 + q * 4 + r;
        C[(size_t)row * N + col] = acc[fm][fn][r];
      }
    }
  }
}

// fp32 -> fp16 convert (vectorized x4)
__global__ __launch_bounds__(256)
void cvt_half_kernel(const float* __restrict__ src, _Float16* __restrict__ dst) {
  const int i = (blockIdx.x * 256 + threadIdx.x) * 4;
  const float4 v = *(const float4*)(src + i);
  half4 o;
  o[0] = (_Float16)v.x; o[1] = (_Float16)v.y;
  o[2] = (_Float16)v.z; o[3] = (_Float16)v.w;
  *(half4*)(dst + i) = o;
}

// fp32 RxC -> fp16 CxR transpose-convert (32x32 LDS tiles)
__global__ __launch_bounds__(256)
void transpose_h_kernel(const float* __restrict__ src, _Float16* __restrict__ dst,
                        int R, int C) {
  __shared__ float t[32][33];
  const int tx = threadIdx.x & 31, ty = threadIdx.x >> 5;
  const int c0 = blockIdx.x * 32, r0 = blockIdx.y * 32;
  #pragma unroll
  for (int s = 0; s < 4; ++s)
    t[ty + s * 8][tx] = src[(size_t)(r0 + ty + s * 8) * C + c0 + tx];
  __syncthreads();
  #pragma unroll
  for (int s = 0; s < 4; ++s)
    dst[(size_t)(c0 + ty + s * 8) * R + r0 + tx] = (_Float16)t[tx][ty + s * 8];
}

// ---------------------------------------------------------------------------
// Classic fp32 SGEMM (kept for the tiny K=64 dt_proj). EPI==1: softplus+bias.
// ---------------------------------------------------------------------------
template<int EPI>
__global__ __launch_bounds__(256)
void sgemm128(const float* __restrict__ A, int lda,
              const float* __restrict__ Bm, const float* __restrict__ bias,
              float* __restrict__ C, int N, int K) {
  __shared__ float As[8][128];
  __shared__ float Bs[8][128];
  const int tid  = threadIdx.x;
  const int m0   = blockIdx.y * 128;
  const int n0   = blockIdx.x * 128;
  const int tx   = tid & 15;
  const int ty   = tid >> 4;
  const int arow = tid >> 1;
  const int acol = (tid & 1) * 4;
  const int brow = tid >> 5;
  const int bcol = (tid & 31) * 4;

  const float* Ap = A + (size_t)(m0 + arow) * lda + acol;
  const float* Bp = Bm + (size_t)brow * N + n0 + bcol;

  float acc[8][8];
  #pragma unroll
  for (int i = 0; i < 8; ++i)
    #pragma unroll
    for (int j = 0; j < 8; ++j) acc[i][j] = 0.f;

  for (int k0 = 0; k0 < K; k0 += 8) {
    const float4 av = *(const float4*)(Ap + k0);
    const float4 bv = *(const float4*)(Bp + (size_t)k0 * N);
    __syncthreads();
    As[acol + 0][arow] = av.x;
    As[acol + 1][arow] = av.y;
    As[acol + 2][arow] = av.z;
    As[acol + 3][arow] = av.w;
    *(float4*)&Bs[brow][bcol] = bv;
    __syncthreads();
    #pragma unroll
    for (int k = 0; k < 8; ++k) {
      float a[8], b[8];
      *(float4*)(a)     = *(const float4*)&As[k][ty * 8];
      *(float4*)(a + 4) = *(const float4*)&As[k][ty * 8 + 4];
      *(float4*)(b)     = *(const float4*)&Bs[k][tx * 8];
      *(float4*)(b + 4) = *(const float4*)&Bs[k][tx * 8 + 4];
      #pragma unroll
      for (int i = 0; i < 8; ++i)
        #pragma unroll
        for (int j = 0; j < 8; ++j)
          acc[i][j] = fmaf(a[i], b[j], acc[i][j]);
    }
  }

  #pragma unroll
  for (int i = 0; i < 8; ++i) {
    float* Cp = C + (size_t)(m0 + ty * 8 + i) * N + n0 + tx * 8;
    #pragma unroll
    for (int j = 0; j < 8; ++j) {
      float v = acc[i][j];
      if (EPI == 1) {
        v += bias[n0 + tx * 8 + j];
        v = fmaxf(v, 0.f) + log1pf(__expf(-fabsf(v)));  // stable softplus
      }
      Cp[j] = v;
    }
  }
}

// Causal depthwise conv (width 4, left pad 3) + bias + silu.
__global__ __launch_bounds__(256)
void conv_silu_kernel(const float* __restrict__ xr, const float* __restrict__ w,
                      const float* __restrict__ cb, float* __restrict__ u) {
  const int idx = blockIdx.x * 256 + threadIdx.x;   // (b*SEQ+t)*ED + d
  const int d = idx & (ED - 1);
  const int t = (idx >> 11) & (SEQ - 1);
  const float4 wv = ((const float4*)w)[d];
  const float* base = xr + (size_t)(idx >> 11) * (2 * ED) + d;
  float acc = cb[d];
  acc = fmaf(wv.w, base[0], acc);
  if (t >= 1) acc = fmaf(wv.z, base[-(2 * ED)], acc);
  if (t >= 2) acc = fmaf(wv.y, base[-2 * (2 * ED)], acc);
  if (t >= 3) acc = fmaf(wv.x, base[-3 * (2 * ED)], acc);
  u[idx] = silu_f(acc);
}

// x_proj split-K=8 partials then reduce (N=96).
__global__ __launch_bounds__(256)
void xproj_kernel(const float* __restrict__ U, const float* __restrict__ W,
                  float* __restrict__ part) {
  __shared__ float Us[32][65];
  __shared__ float Ws[32][96];
  const int tid = threadIdx.x;
  const int m0 = blockIdx.x * 64;
  const int ks = blockIdx.y * 256;
  const int tx = tid & 15;
  const int ty = tid >> 4;
  const int lm = tid >> 2;
  const int lk = (tid & 3) * 8;

  float acc[4][6];
  #pragma unroll
  for (int i = 0; i < 4; ++i)
    #pragma unroll
    for (int j = 0; j < 6; ++j) acc[i][j] = 0.f;

  for (int k0 = ks; k0 < ks + 256; k0 += 32) {
    __syncthreads();
    const float* up = U + (size_t)(m0 + lm) * ED + k0 + lk;
    const float4 u0 = *(const float4*)(up);
    const float4 u1 = *(const float4*)(up + 4);
    Us[lk + 0][lm] = u0.x; Us[lk + 1][lm] = u0.y;
    Us[lk + 2][lm] = u0.z; Us[lk + 3][lm] = u0.w;
    Us[lk + 4][lm] = u1.x; Us[lk + 5][lm] = u1.y;
    Us[lk + 6][lm] = u1.z; Us[lk + 7][lm] = u1.w;
    for (int i = tid; i < 32 * 96; i += 256) {
      const int kk = i / 96, nn = i - kk * 96;
      Ws[kk][nn] = W[(size_t)(k0 + kk) * 96 + nn];
    }
    __syncthreads();
    #pragma unroll
    for (int k = 0; k < 32; ++k) {
      float a[4], wv[6];
      #pragma unroll
      for (int i = 0; i < 4; ++i) a[i] = Us[k][ty * 4 + i];
      #pragma unroll
      for (int j = 0; j < 6; ++j) wv[j] = Ws[k][tx * 6 + j];
      #pragma unroll
      for (int i = 0; i < 4; ++i)
        #pragma unroll
        for (int j = 0; j < 6; ++j)
          acc[i][j] = fmaf(a[i], wv[j], acc[i][j]);
    }
  }
  float* pp = part + (size_t)blockIdx.y * NROWS * 96;
  #pragma unroll
  for (int i = 0; i < 4; ++i)
    #pragma unroll
    for (int j = 0; j < 6; ++j)
      pp[(size_t)(m0 + ty * 4 + i) * 96 + tx * 6 + j] = acc[i][j];
}

__global__ __launch_bounds__(256)
void xproj_reduce(const float* __restrict__ part, float* __restrict__ dbc) {
  const int idx = blockIdx.x * 256 + threadIdx.x;
  float s = 0.f;
  #pragma unroll
  for (int r = 0; r < 8; ++r) s += part[(size_t)r * NROWS * 96 + idx];
  dbc[idx] = s;
}

// Chunked selective scan (3 passes).
__global__ __launch_bounds__(256)
void scan_chunk_summary(const float* __restrict__ dt, const float* __restrict__ u,
                        const float* __restrict__ dbc, const float* __restrict__ A_log,
                        float* __restrict__ Pbuf, float* __restrict__ Sbuf) {
  const unsigned tau = blockIdx.x * 256 + threadIdx.x;
  const int n  = tau & 15;
  const int bd = (tau >> 4) & (BATCH * ED - 1);
  const int g  = tau >> 16;
  const int b = bd >> 11, d = bd & (ED - 1);
  const float Adn = -__expf(A_log[d * NS + n]);
  const size_t row0 = (size_t)b * SEQ + (size_t)g * CLEN;
  const float* dtp = dt + row0 * ED + d;
  const float* up  = u  + row0 * ED + d;
  const float* Bp  = dbc + row0 * 96 + DR + n;

  float P = 1.f, S = 0.f;
  for (int t = 0; t < CLEN; ++t) {
    const float dti = dtp[(size_t)t * ED];
    const float ui  = up[(size_t)t * ED];
    const float Bi  = Bp[(size_t)t * 96];
    const float a = __expf(dti * Adn);
    S = fmaf(S, a, dti * ui * Bi);
    P *= a;
  }
  const unsigned c = tau & (CSTATES - 1);
  Pbuf[(size_t)g * CSTATES + c] = P;
  Sbuf[(size_t)g * CSTATES + c] = S;
}

__global__ __launch_bounds__(256)
void scan_chunk_compose(float* __restrict__ Pbuf, const float* __restrict__ Sbuf) {
  const unsigned c = blockIdx.x * 256 + threadIdx.x;
  float h = 0.f;
  #pragma unroll
  for (int g = 0; g < NCHUNK; ++g) {
    const size_t idx = (size_t)g * CSTATES + c;
    const float p = Pbuf[idx], s = Sbuf[idx];
    Pbuf[idx] = h;
    h = fmaf(p, h, s);
  }
}

__global__ __launch_bounds__(256)
void scan_chunk_apply(const float* __restrict__ dt, const float* __restrict__ u,
                      const float* __restrict__ dbc, const float* __restrict__ A_log,
                      const float* __restrict__ Dp, const float* __restrict__ Pbuf,
                      float* __restrict__ y) {
  const unsigned tau = blockIdx.x * 256 + threadIdx.x;
  const int n  = tau & 15;
  const int bd = (tau >> 4) & (BATCH * ED - 1);
  const int g  = tau >> 16;
  const int b = bd >> 11, d = bd & (ED - 1);
  const float Adn = -__expf(A_log[d * NS + n]);
  const float Dd = Dp[d];
  const size_t row0 = (size_t)b * SEQ + (size_t)g * CLEN;
  const float* dtp = dt + row0 * ED + d;
  const float* up  = u  + row0 * ED + d;
  const float* Bp  = dbc + row0 * 96 + DR + n;
  const float* Cp  = dbc + row0 * 96 + DR + NS + n;
  float* yp = y + row0 * ED + d;

  const unsigned c = tau & (CSTATES - 1);
  float h = Pbuf[(size_t)g * CSTATES + c];

  for (int t = 0; t < CLEN; ++t) {
    const float dti = dtp[(size_t)t * ED];
    const float ui  = up[(size_t)t * ED];
    const float Bi  = Bp[(size_t)t * 96];
    const float Ci  = Cp[(size_t)t * 96];
    const float a = __expf(dti * Adn);
    h = fmaf(h, a, dti * ui * Bi);
    float yv = h * Ci;
    yv += __shfl_xor(yv, 1);
    yv += __shfl_xor(yv, 2);
    yv += __shfl_xor(yv, 4);
    yv += __shfl_xor(yv, 8);
    if (n == 0) yp[(size_t)t * ED] = fmaf(Dd, ui, yv);
  }
}

// y_h(fp16) = y_ssm * silu(res);  res = right half of xr rows.
__global__ __launch_bounds__(256)
void gate_kernel(const float* __restrict__ yssm, const float* __restrict__ xr,
                 _Float16* __restrict__ y) {
  const int idx = blockIdx.x * 256 + threadIdx.x;
  const int d = idx & (ED - 1);
  const size_t row = (size_t)(idx >> 11);
  const float r = xr[row * (2 * ED) + ED + d];
  y[idx] = (_Float16)(yssm[idx] * silu_f(r));
}

extern "C" void kernel_launch(void* const* d_in, const int* in_sizes, int n_in,
                              void* d_out, int out_size, void* d_ws, size_t ws_size,
                              hipStream_t stream) {
  (void)in_sizes; (void)n_in; (void)out_size; (void)ws_size;
  const float* x     = (const float*)d_in[0];
  const float* Win   = (const float*)d_in[1];
  const float* convw = (const float*)d_in[2];
  const float* convb = (const float*)d_in[3];
  const float* Wx    = (const float*)d_in[4];
  const float* Wdt   = (const float*)d_in[5];
  const float* bdt   = (const float*)d_in[6];
  const float* Alog  = (const float*)d_in[7];
  const float* Dp    = (const float*)d_in[8];
  const float* Wout  = (const float*)d_in[9];

  float* ws   = (float*)d_ws;
  float* xr   = ws + OFF_XR;
  float* u    = ws + OFF_U;
  float* dt   = ws + OFF_DT;
  float* dbc  = ws + OFF_DBC;
  float* part = ws + OFF_PART;
  float* Pbuf = part;
  float* Sbuf = part + (size_t)NCHUNK * CSTATES;
  float* out  = (float*)d_out;

  // fp16 staging buffers in dead regions:
  // x_h + Wint live in the dt region (dt written later, after in_proj GEMM).
  _Float16* x_h   = (_Float16*)(ws + OFF_DT);             // 4M halves = 8MB
  _Float16* Wint  = (_Float16*)(ws + OFF_DT + 2097152);   // 4M halves = 8MB
  _Float16* y_h   = (_Float16*)(ws + OFF_U);              // 8M halves = 16MB (u dead post-scan)
  _Float16* Woutt = (_Float16*)(ws + OFF_PART);           // 2M halves = 4MB (part dead post-scan)

  // 0) fp32->fp16 conversions for in_proj operands
  cvt_half_kernel<<<(NROWS * DM) / 1024, 256, 0, stream>>>(x, x_h);
  transpose_h_kernel<<<dim3((2 * ED) / 32, DM / 32), 256, 0, stream>>>(
      Win, Wint, DM, 2 * ED);
  // 1) xr = x @ in_proj_w  (MFMA fp16, fp32 accum)
  hgemm<128, 2, 2><<<dim3((2 * ED) / 128, NROWS / 128), 256, 0, stream>>>(
      x_h, DM, Wint, DM, xr, 2 * ED, DM);
  // 2) u = silu(causal_dwconv(xb) + conv_b)
  conv_silu_kernel<<<(NROWS * ED) / 256, 256, 0, stream>>>(xr, convw, convb, u);
  // 3) dbc = u @ x_proj_w  (split-K=8 + reduce)
  xproj_kernel<<<dim3(NROWS / 64, 8), 256, 0, stream>>>(u, Wx, part);
  xproj_reduce<<<(NROWS * 96) / 256, 256, 0, stream>>>(part, dbc);
  // 4) dt = softplus(dbc[:, :64] @ dt_proj_w + dt_proj_b)  (overwrites x_h/Wint: dead)
  sgemm128<1><<<dim3(ED / 128, NROWS / 128), 256, 0, stream>>>(
      dbc, 96, Wdt, bdt, dt, ED, DR);
  // 5) chunked selective scan -> y_ssm (in-place over dt)
  scan_chunk_summary<<<(CSTATES * NCHUNK) / 256, 256, 0, stream>>>(
      dt, u, dbc, Alog, Pbuf, Sbuf);
  scan_chunk_compose<<<CSTATES / 256, 256, 0, stream>>>(Pbuf, Sbuf);
  scan_chunk_apply<<<(CSTATES * NCHUNK) / 256, 256, 0, stream>>>(
      dt, u, dbc, Alog, Dp, Pbuf, dt);
  // 6) Wout transpose-convert (part region free now) + gate to fp16
  transpose_h_kernel<<<dim3(DM / 32, ED / 32), 256, 0, stream>>>(
      Wout, Woutt, ED, DM);
  gate_kernel<<<(NROWS * ED) / 256, 256, 0, stream>>>(dt, xr, y_h);
  // 7) out = y @ out_proj_w  (MFMA fp16)
  hgemm<64, 4, 1><<<dim3(DM / 64, NROWS / 128), 256, 0, stream>>>(
      y_h, ED, Woutt, ED, out, DM, ED);
}

// Round 4
// 374.566 us; speedup vs baseline: 4.1127x; 1.3541x over previous
//
#include <hip/hip_runtime.h>
#include <cstddef>
#include <cstdint>

// Problem constants
#define BATCH 2
#define SEQ   2048
#define DM    1024   // d_model
#define ED    2048   // d_inner
#define NS    16     // d_state
#define DR    64     // dt_rank
#define NROWS (BATCH*SEQ)  // 4096

// Chunked-scan parameters: SEQ = NCHUNK * CLEN
#define NCHUNK 32
#define CLEN   64
#define CSTATES (BATCH*ED*NS)   // 65536 independent recurrences

// ---------------------------------------------------------------------------
// workspace layout (float offsets), total 37,093,376 floats = 148.4 MB
// ---------------------------------------------------------------------------
#define OFF_XB    ((size_t)0)          //  8,388,608 f  (B,L,ED) fp32 conv input
#define OFF_RESH  ((size_t)8388608)    //  4,194,304 f  (B,L,ED) fp16 silu(res); apply overwrites with y_h
#define OFF_U     ((size_t)12582912)   //  8,388,608 f  (B,L,ED) fp32
#define OFF_DT    ((size_t)20971520)   //  8,388,608 f  (B,L,ED) fp32; staging x_h/Wint/u_h before dt written
#define OFF_DBC   ((size_t)29360128)   //    393,216 f  (B,L,96)
#define OFF_PART  ((size_t)29753344)   //  7,340,032 f  xproj partials / P / S / Woutt / Wxt
// DT-region staging (dead once sgemm_dt writes dt):
//   x_h  @ OFF_DT          : 4M halves (2,097,152 f)
//   Wint @ OFF_DT+2097152  : 4M halves (2,097,152 f)
//   u_h  @ OFF_DT+4194304  : 8.4M halves (4,194,304 f)
// PART-region: xproj partials @ +0 (3,145,728 f, dead after reduce)
//   P @ +0 (2,097,152) · S @ +2,097,152 (2,097,152)
//   Woutt @ +4,194,304 (2M halves = 1,048,576 f) · Wxt @ +5,242,880 (98,304 f)

typedef _Float16 half8 __attribute__((ext_vector_type(8)));
typedef _Float16 half4 __attribute__((ext_vector_type(4)));
typedef float    floatx4 __attribute__((ext_vector_type(4)));

__device__ __forceinline__ float silu_f(float x) { return x / (1.f + __expf(-x)); }

__device__ __forceinline__ void gload_lds16(const _Float16* g, _Float16* l) {
  __builtin_amdgcn_global_load_lds(
      (const __attribute__((address_space(1))) void*)g,
      (__attribute__((address_space(3))) void*)l, 16, 0, 0);
}

// ---------------------------------------------------------------------------
// fp16 MFMA GEMM: C(MxN fp32) = A(MxK fp16 rm) @ Bt^T (Bt[n][k] fp16, ldb).
// BM=128, BK=32, 256 threads (4 waves, WGM x WGN), 16x16x32 MFMA.
// LDS XOR swizzle c_l = c_g ^ ((row>>1)&3) keeps global_load_lds lane order
// while making frag ds_read_b128 a free 2-way alias.
// EPI 0: plain fp32 store. EPI 2: col<ED -> C=xb fp32 (stride ED);
//        col>=ED -> Ch = (fp16)silu(v) (stride ED).
// KSPLIT: blockIdx.z slices K; C += z*cslice (partials reduced separately).
// ---------------------------------------------------------------------------
template<int BN, int WGM, int WGN, int EPI, int KSPLIT>
__global__ __launch_bounds__(256)
void hgemm(const _Float16* __restrict__ A, int lda,
           const _Float16* __restrict__ Bt, int ldb,
           float* __restrict__ C, _Float16* __restrict__ Ch,
           size_t cslice, int N, int K) {
  constexpr int BM = 128;
  constexpr int FM = BM / 16 / WGM;
  constexpr int FN = BN / 16 / WGN;
  __shared__ _Float16 sA[BM * 32];
  __shared__ _Float16 sB[BN * 32];
  const int tid = threadIdx.x;
  const int ln  = tid & 63;
  const int wid = tid >> 6;
  const int wm  = wid % WGM;
  const int wn  = wid / WGM;
  const int m0  = blockIdx.y * BM;
  const int n0  = blockIdx.x * BN;
  const int l15 = ln & 15;
  const int q   = ln >> 4;

  const int kLen = K / KSPLIT;
  const int kbeg = blockIdx.z * kLen;
  if (KSPLIT > 1) C += (size_t)blockIdx.z * cslice;

  floatx4 acc[FM][FN];
  #pragma unroll
  for (int i = 0; i < FM; ++i)
    #pragma unroll
    for (int j = 0; j < FN; ++j)
      acc[i][j] = floatx4{0.f, 0.f, 0.f, 0.f};

  for (int k0 = kbeg; k0 < kbeg + kLen; k0 += 32) {
    __syncthreads();
    #pragma unroll
    for (int s = 0; s < (BM * 4 + 255) / 256; ++s) {
      const int i = s * 256 + tid;
      if (BM * 4 % 256 == 0 || i < BM * 4) {
        const int m = i >> 2;
        const int cg = (i & 3) ^ ((m >> 1) & 3);
        gload_lds16(A + (size_t)(m0 + m) * lda + k0 + cg * 8, sA + i * 8);
      }
    }
    #pragma unroll
    for (int s = 0; s < (BN * 4 + 255) / 256; ++s) {
      const int i = s * 256 + tid;
      if (BN * 4 % 256 == 0 || i < BN * 4) {
        const int n = i >> 2;
        const int cg = (i & 3) ^ ((n >> 1) & 3);
        gload_lds16(Bt + (size_t)(n0 + n) * ldb + k0 + cg * 8, sB + i * 8);
      }
    }
    __syncthreads();

    half8 af[FM], bf[FN];
    #pragma unroll
    for (int fm = 0; fm < FM; ++fm) {
      const int mr = wm * FM * 16 + fm * 16 + l15;
      const int cl = q ^ ((mr >> 1) & 3);
      af[fm] = *(const half8*)(sA + mr * 32 + cl * 8);
    }
    #pragma unroll
    for (int fn = 0; fn < FN; ++fn) {
      const int nr = wn * FN * 16 + fn * 16 + l15;
      const int cl = q ^ ((nr >> 1) & 3);
      bf[fn] = *(const half8*)(sB + nr * 32 + cl * 8);
    }
    #pragma unroll
    for (int fm = 0; fm < FM; ++fm)
      #pragma unroll
      for (int fn = 0; fn < FN; ++fn)
        acc[fm][fn] = __builtin_amdgcn_mfma_f32_16x16x32_f16(
            af[fm], bf[fn], acc[fm][fn], 0, 0, 0);
  }

  // C/D layout: col = lane&15, row = (lane>>4)*4 + reg  (m89/m91 verified)
  #pragma unroll
  for (int fm = 0; fm < FM; ++fm) {
    #pragma unroll
    for (int fn = 0; fn < FN; ++fn) {
      const int col = n0 + wn * FN * 16 + fn * 16 + l15;
      #pragma unroll
      for (int r = 0; r < 4; ++r) {
        const int row = m0 + wm * FM * 16 + fm * 16 + q * 4 + r;
        const float v = acc[fm][fn][r];
        if (EPI == 2) {
          if (col < ED) C[(size_t)row * ED + col] = v;
          else          Ch[(size_t)row * ED + (col - ED)] = (_Float16)silu_f(v);
        } else {
          C[(size_t)row * N + col] = v;
        }
      }
    }
  }
}

// fp32 -> fp16 convert (x4)
__global__ __launch_bounds__(256)
void cvt_half_kernel(const float* __restrict__ src, _Float16* __restrict__ dst) {
  const int i = (blockIdx.x * 256 + threadIdx.x) * 4;
  const float4 v = *(const float4*)(src + i);
  half4 o;
  o[0] = (_Float16)v.x; o[1] = (_Float16)v.y;
  o[2] = (_Float16)v.z; o[3] = (_Float16)v.w;
  *(half4*)(dst + i) = o;
}

// fp32 RxC -> fp16 CxR transpose-convert (32x32 LDS tiles)
__global__ __launch_bounds__(256)
void transpose_h_kernel(const float* __restrict__ src, _Float16* __restrict__ dst,
                        int R, int C) {
  __shared__ float t[32][33];
  const int tx = threadIdx.x & 31, ty = threadIdx.x >> 5;
  const int c0 = blockIdx.x * 32, r0 = blockIdx.y * 32;
  #pragma unroll
  for (int s = 0; s < 4; ++s)
    t[ty + s * 8][tx] = src[(size_t)(r0 + ty + s * 8) * C + c0 + tx];
  __syncthreads();
  #pragma unroll
  for (int s = 0; s < 4; ++s)
    dst[(size_t)(c0 + ty + s * 8) * R + r0 + tx] = (_Float16)t[tx][ty + s * 8];
}

// ---------------------------------------------------------------------------
// fp32 SGEMM for dt_proj (K=64, fp32 precision kept for the scan's dt).
// EPI==1: softplus(acc + bias[n]).
// ---------------------------------------------------------------------------
template<int EPI>
__global__ __launch_bounds__(256)
void sgemm128(const float* __restrict__ A, int lda,
              const float* __restrict__ Bm, const float* __restrict__ bias,
              float* __restrict__ C, int N, int K) {
  __shared__ float As[8][128];
  __shared__ float Bs[8][128];
  const int tid  = threadIdx.x;
  const int m0   = blockIdx.y * 128;
  const int n0   = blockIdx.x * 128;
  const int tx   = tid & 15;
  const int ty   = tid >> 4;
  const int arow = tid >> 1;
  const int acol = (tid & 1) * 4;
  const int brow = tid >> 5;
  const int bcol = (tid & 31) * 4;

  const float* Ap = A + (size_t)(m0 + arow) * lda + acol;
  const float* Bp = Bm + (size_t)brow * N + n0 + bcol;

  float acc[8][8];
  #pragma unroll
  for (int i = 0; i < 8; ++i)
    #pragma unroll
    for (int j = 0; j < 8; ++j) acc[i][j] = 0.f;

  for (int k0 = 0; k0 < K; k0 += 8) {
    const float4 av = *(const float4*)(Ap + k0);
    const float4 bv = *(const float4*)(Bp + (size_t)k0 * N);
    __syncthreads();
    As[acol + 0][arow] = av.x;
    As[acol + 1][arow] = av.y;
    As[acol + 2][arow] = av.z;
    As[acol + 3][arow] = av.w;
    *(float4*)&Bs[brow][bcol] = bv;
    __syncthreads();
    #pragma unroll
    for (int k = 0; k < 8; ++k) {
      float a[8], b[8];
      *(float4*)(a)     = *(const float4*)&As[k][ty * 8];
      *(float4*)(a + 4) = *(const float4*)&As[k][ty * 8 + 4];
      *(float4*)(b)     = *(const float4*)&Bs[k][tx * 8];
      *(float4*)(b + 4) = *(const float4*)&Bs[k][tx * 8 + 4];
      #pragma unroll
      for (int i = 0; i < 8; ++i)
        #pragma unroll
        for (int j = 0; j < 8; ++j)
          acc[i][j] = fmaf(a[i], b[j], acc[i][j]);
    }
  }

  #pragma unroll
  for (int i = 0; i < 8; ++i) {
    float* Cp = C + (size_t)(m0 + ty * 8 + i) * N + n0 + tx * 8;
    #pragma unroll
    for (int j = 0; j < 8; ++j) {
      float v = acc[i][j];
      if (EPI == 1) {
        v += bias[n0 + tx * 8 + j];
        v = fmaxf(v, 0.f) + log1pf(__expf(-fabsf(v)));  // stable softplus
      }
      Cp[j] = v;
    }
  }
}

// Causal depthwise conv (width 4, left pad 3) + bias + silu -> u fp32 + u_h fp16.
__global__ __launch_bounds__(256)
void conv_silu_kernel(const float* __restrict__ xb, const float* __restrict__ w,
                      const float* __restrict__ cb, float* __restrict__ u,
                      _Float16* __restrict__ u_h) {
  const int idx = blockIdx.x * 256 + threadIdx.x;   // (b*SEQ+t)*ED + d
  const int d = idx & (ED - 1);
  const int t = (idx >> 11) & (SEQ - 1);
  const float4 wv = ((const float4*)w)[d];
  const float* base = xb + (size_t)(idx >> 11) * ED + d;
  float acc = cb[d];
  acc = fmaf(wv.w, base[0], acc);
  if (t >= 1) acc = fmaf(wv.z, base[-ED], acc);
  if (t >= 2) acc = fmaf(wv.y, base[-2 * ED], acc);
  if (t >= 3) acc = fmaf(wv.x, base[-3 * ED], acc);
  const float v = silu_f(acc);
  u[idx] = v;
  u_h[idx] = (_Float16)v;
}

__global__ __launch_bounds__(256)
void xproj_reduce(const float* __restrict__ part, float* __restrict__ dbc) {
  const int idx = blockIdx.x * 256 + threadIdx.x;  // < NROWS*96
  float s = 0.f;
  #pragma unroll
  for (int r = 0; r < 8; ++r) s += part[(size_t)r * NROWS * 96 + idx];
  dbc[idx] = s;
}

// ---------------------------------------------------------------------------
// Channel-per-lane chunked scan. Thread = (b, d, chunk g); 16 states h[n]
// in registers. dt/u loads coalesced (lane = d); B/C wave-uniform (scalar);
// n-reduction in-register (no shuffles).
// ---------------------------------------------------------------------------
__global__ __launch_bounds__(256)
void scan2_summary(const float* __restrict__ dt, const float* __restrict__ u,
                   const float* __restrict__ dbc, const float* __restrict__ A_log,
                   float* __restrict__ Pbuf, float* __restrict__ Sbuf) {
  const int d = blockIdx.x * 256 + threadIdx.x;   // grid.x = ED/256
  const int b = blockIdx.y;
  const int g = blockIdx.z;

  float Adn[16];
  {
    const float4* al = (const float4*)(A_log + (size_t)d * NS);
    #pragma unroll
    for (int i = 0; i < 4; ++i) {
      const float4 v = al[i];
      Adn[i * 4 + 0] = -__expf(v.x); Adn[i * 4 + 1] = -__expf(v.y);
      Adn[i * 4 + 2] = -__expf(v.z); Adn[i * 4 + 3] = -__expf(v.w);
    }
  }
  float P[16], S[16];
  #pragma unroll
  for (int n = 0; n < 16; ++n) { P[n] = 1.f; S[n] = 0.f; }

  const size_t row0 = (size_t)b * SEQ + (size_t)g * CLEN;
  const float* dtp = dt + row0 * ED + d;
  const float* up  = u  + row0 * ED + d;

  for (int t = 0; t < CLEN; ++t) {
    const float dti = dtp[(size_t)t * ED];
    const float ui  = up[(size_t)t * ED];
    const float4* bc = (const float4*)(dbc + (row0 + t) * 96 + DR);  // uniform
    float Bv[16];
    #pragma unroll
    for (int i = 0; i < 4; ++i) {
      const float4 v = bc[i];
      Bv[i * 4 + 0] = v.x; Bv[i * 4 + 1] = v.y;
      Bv[i * 4 + 2] = v.z; Bv[i * 4 + 3] = v.w;
    }
    const float dtu = dti * ui;
    #pragma unroll
    for (int n = 0; n < 16; ++n) {
      const float a = __expf(dti * Adn[n]);
      S[n] = fmaf(S[n], a, dtu * Bv[n]);
      P[n] *= a;
    }
  }
  const size_t c0 = (size_t)g * CSTATES + ((size_t)(b * ED + d)) * NS;
  #pragma unroll
  for (int i = 0; i < 4; ++i) {
    *(float4*)(Pbuf + c0 + i * 4) = float4{P[i*4], P[i*4+1], P[i*4+2], P[i*4+3]};
    *(float4*)(Sbuf + c0 + i * 4) = float4{S[i*4], S[i*4+1], S[i*4+2], S[i*4+3]};
  }
}

// Compose chunk summaries -> each chunk's entry state h0 (in-place over Pbuf).
__global__ __launch_bounds__(256)
void scan2_compose(float* __restrict__ Pbuf, const float* __restrict__ Sbuf) {
  const unsigned c = blockIdx.x * 256 + threadIdx.x;  // < CSTATES
  float h = 0.f;
  for (int g = 0; g < NCHUNK; ++g) {
    const size_t idx = (size_t)g * CSTATES + c;
    const float p = Pbuf[idx], s = Sbuf[idx];
    Pbuf[idx] = h;
    h = fmaf(p, h, s);
  }
}

// Final pass: recurrence from h0; fused gate: y_h = (fp16)(y * silu_res),
// written IN-PLACE over resh (same element, same thread, read-before-write).
__global__ __launch_bounds__(256)
void scan2_apply(const float* __restrict__ dt, const float* __restrict__ u,
                 const float* __restrict__ dbc, const float* __restrict__ A_log,
                 const float* __restrict__ Dp, const float* __restrict__ Pbuf,
                 _Float16* __restrict__ resh) {
  const int d = blockIdx.x * 256 + threadIdx.x;
  const int b = blockIdx.y;
  const int g = blockIdx.z;

  float Adn[16];
  {
    const float4* al = (const float4*)(A_log + (size_t)d * NS);
    #pragma unroll
    for (int i = 0; i < 4; ++i) {
      const float4 v = al[i];
      Adn[i * 4 + 0] = -__expf(v.x); Adn[i * 4 + 1] = -__expf(v.y);
      Adn[i * 4 + 2] = -__expf(v.z); Adn[i * 4 + 3] = -__expf(v.w);
    }
  }
  const float Dd = Dp[d];
  float h[16];
  const size_t c0 = (size_t)g * CSTATES + ((size_t)(b * ED + d)) * NS;
  #pragma unroll
  for (int i = 0; i < 4; ++i) {
    const float4 v = *(const float4*)(Pbuf + c0 + i * 4);
    h[i * 4 + 0] = v.x; h[i * 4 + 1] = v.y;
    h[i * 4 + 2] = v.z; h[i * 4 + 3] = v.w;
  }

  const size_t row0 = (size_t)b * SEQ + (size_t)g * CLEN;
  const float* dtp = dt + row0 * ED + d;
  const float* up  = u  + row0 * ED + d;
  _Float16* rp = resh + row0 * ED + d;

  for (int t = 0; t < CLEN; ++t) {
    const float dti = dtp[(size_t)t * ED];
    const float ui  = up[(size_t)t * ED];
    const float4* bc = (const float4*)(dbc + (row0 + t) * 96 + DR);  // uniform
    float Bv[16], Cv[16];
    #pragma unroll
    for (int i = 0; i < 4; ++i) {
      const float4 v = bc[i];
      Bv[i * 4 + 0] = v.x; Bv[i * 4 + 1] = v.y;
      Bv[i * 4 + 2] = v.z; Bv[i * 4 + 3] = v.w;
      const float4 w = bc[4 + i];
      Cv[i * 4 + 0] = w.x; Cv[i * 4 + 1] = w.y;
      Cv[i * 4 + 2] = w.z; Cv[i * 4 + 3] = w.w;
    }
    const float dtu = dti * ui;
    float y = Dd * ui;
    #pragma unroll
    for (int n = 0; n < 16; ++n) {
      const float a = __expf(dti * Adn[n]);
      h[n] = fmaf(h[n], a, dtu * Bv[n]);
      y = fmaf(h[n], Cv[n], y);
    }
    const float sres = (float)rp[(size_t)t * ED];   // silu(res), read before write
    rp[(size_t)t * ED] = (_Float16)(y * sres);      // y_h in-place
  }
}

extern "C" void kernel_launch(void* const* d_in, const int* in_sizes, int n_in,
                              void* d_out, int out_size, void* d_ws, size_t ws_size,
                              hipStream_t stream) {
  (void)in_sizes; (void)n_in; (void)out_size; (void)ws_size;
  const float* x     = (const float*)d_in[0];
  const float* Win   = (const float*)d_in[1];
  const float* convw = (const float*)d_in[2];
  const float* convb = (const float*)d_in[3];
  const float* Wx    = (const float*)d_in[4];
  const float* Wdt   = (const float*)d_in[5];
  const float* bdt   = (const float*)d_in[6];
  const float* Alog  = (const float*)d_in[7];
  const float* Dp    = (const float*)d_in[8];
  const float* Wout  = (const float*)d_in[9];

  float* ws   = (float*)d_ws;
  float* xb   = ws + OFF_XB;
  _Float16* resh = (_Float16*)(ws + OFF_RESH);
  float* u    = ws + OFF_U;
  float* dt   = ws + OFF_DT;
  float* dbc  = ws + OFF_DBC;
  float* part = ws + OFF_PART;
  float* Pbuf = part;                                  // 2,097,152 f
  float* Sbuf = part + (size_t)NCHUNK * CSTATES;       // 2,097,152 f
  _Float16* Woutt = (_Float16*)(part + 4194304);       // 2M halves
  _Float16* Wxt   = (_Float16*)(part + 5242880);       // 192K halves
  float* out  = (float*)d_out;

  _Float16* x_h  = (_Float16*)(ws + OFF_DT);           // 4M halves
  _Float16* Wint = (_Float16*)(ws + OFF_DT + 2097152); // 4M halves
  _Float16* u_h  = (_Float16*)(ws + OFF_DT + 4194304); // 8.4M halves

  // 0) fp16 operand prep
  cvt_half_kernel<<<(NROWS * DM) / 1024, 256, 0, stream>>>(x, x_h);
  transpose_h_kernel<<<dim3((2 * ED) / 32, DM / 32), 256, 0, stream>>>(
      Win, Wint, DM, 2 * ED);
  transpose_h_kernel<<<dim3(96 / 32, ED / 32), 256, 0, stream>>>(
      Wx, Wxt, ED, 96);
  transpose_h_kernel<<<dim3(DM / 32, ED / 32), 256, 0, stream>>>(
      Wout, Woutt, ED, DM);
  // 1) in_proj: xb fp32 + resh = (fp16)silu(res), split epilogue
  hgemm<128, 2, 2, 2, 1><<<dim3((2 * ED) / 128, NROWS / 128), 256, 0, stream>>>(
      x_h, DM, Wint, DM, xb, resh, 0, 2 * ED, DM);
  // 2) u = silu(causal_dwconv(xb) + conv_b), fp32 + fp16
  conv_silu_kernel<<<(NROWS * ED) / 256, 256, 0, stream>>>(xb, convw, convb, u, u_h);
  // 3) dbc = u @ x_proj_w  (MFMA, split-K=8 + reduce)
  hgemm<96, 4, 1, 0, 8><<<dim3(1, NROWS / 128, 8), 256, 0, stream>>>(
      u_h, ED, Wxt, ED, part, nullptr, (size_t)NROWS * 96, 96, ED);
  xproj_reduce<<<(NROWS * 96) / 256, 256, 0, stream>>>(part, dbc);
  // 4) dt = softplus(dbc[:, :64] @ dt_proj_w + dt_proj_b)  (fp32; overwrites staging)
  sgemm128<1><<<dim3(ED / 128, NROWS / 128), 256, 0, stream>>>(
      dbc, 96, Wdt, bdt, dt, ED, DR);
  // 5) chunked scan, channel-per-lane
  scan2_summary<<<dim3(ED / 256, BATCH, NCHUNK), 256, 0, stream>>>(
      dt, u, dbc, Alog, Pbuf, Sbuf);
  scan2_compose<<<CSTATES / 256, 256, 0, stream>>>(Pbuf, Sbuf);
  scan2_apply<<<dim3(ED / 256, BATCH, NCHUNK), 256, 0, stream>>>(
      dt, u, dbc, Alog, Dp, Pbuf, resh);
  // 6) out = y_h @ out_proj_w  (MFMA)
  hgemm<64, 4, 1, 0, 1><<<dim3(DM / 64, NROWS / 128), 256, 0, stream>>>(
      resh, ED, Woutt, ED, out, nullptr, 0, DM, ED);
}

// Round 5
// 364.461 us; speedup vs baseline: 4.2268x; 1.0277x over previous
//
#include <hip/hip_runtime.h>
#include <cstddef>
#include <cstdint>

// Problem constants
#define BATCH 2
#define SEQ   2048
#define DM    1024   // d_model
#define ED    2048   // d_inner
#define NS    16     // d_state
#define DR    64     // dt_rank
#define NROWS (BATCH*SEQ)  // 4096

// Chunked-scan parameters: SEQ = NCHUNK * CLEN
#define NCHUNK 64
#define CLEN   32
#define CSTATES (BATCH*ED*NS)   // 65536 independent recurrences

// ---------------------------------------------------------------------------
// workspace layout (float offsets), total 37,093,376 floats = 148.4 MB
// ---------------------------------------------------------------------------
#define OFF_XB    ((size_t)0)          //  8,388,608 f  (B,L,ED) fp32 conv input (read by conv + both scan passes)
#define OFF_RESH  ((size_t)8388608)    //  4,194,304 f  (B,L,ED) fp16 silu(res); apply overwrites with y_h
#define OFF_PS    ((size_t)12582912)   //  8,388,608 f  P (4,194,304) + S (4,194,304) chunk summaries
#define OFF_DT    ((size_t)20971520)   //  8,388,608 f  dt fp32; staging x_h/Wint/u_h before dt written
#define OFF_DBC   ((size_t)29360128)   //    393,216 f  (B,L,96) fp32
#define OFF_PART  ((size_t)29753344)   //  7,340,032 f  xproj partials / Woutt / Wxt / dbc64_h / Wdtt
// DT-region staging (dead once dt hgemm writes dt):
//   x_h  @ OFF_DT            : 4M halves (2,097,152 f)
//   Wint @ OFF_DT+2,097,152  : 4M halves (2,097,152 f)
//   u_h  @ OFF_DT+4,194,304  : 8.4M halves (4,194,304 f)
// PART-region:
//   partials @ +0 (3,145,728 f, dead after reduce)
//   Woutt  @ +4,194,304 (1,048,576 f = 2M halves)
//   Wxt    @ +5,242,880 (98,304 f)
//   dbc64h @ +5,341,184 (131,072 f = 256K halves)
//   Wdtt   @ +5,472,256 (65,536 f = 128K halves)

typedef _Float16 half8 __attribute__((ext_vector_type(8)));
typedef _Float16 half4 __attribute__((ext_vector_type(4)));
typedef float    floatx4 __attribute__((ext_vector_type(4)));

__device__ __forceinline__ float silu_f(float x) { return x / (1.f + __expf(-x)); }

__device__ __forceinline__ void gload_lds16(const _Float16* g, _Float16* l) {
  __builtin_amdgcn_global_load_lds(
      (const __attribute__((address_space(1))) void*)g,
      (__attribute__((address_space(3))) void*)l, 16, 0, 0);
}

// ---------------------------------------------------------------------------
// fp16 MFMA GEMM: C(MxN fp32) = A(MxK fp16 rm, lda) @ Bt^T (Bt[n][k] fp16, ldb).
// BM=128, BK=32, 256 threads (4 waves, WGM x WGN), 16x16x32 MFMA.
// LDS XOR swizzle c_l = c_g ^ ((row>>1)&3): keeps global_load_lds lane order,
// makes frag ds_read_b128 a free 2-way bank alias.
// EPI 0: plain fp32 store.
// EPI 2: col<ED -> C=xb fp32 (stride ED); col>=ED -> Ch=(fp16)silu(v) (stride ED).
// EPI 3: C = softplus(v + bias[col]) fp32 (dt_proj).
// KSPLIT: blockIdx.z slices K; C += z*cslice.
// ---------------------------------------------------------------------------
template<int BN, int WGM, int WGN, int EPI, int KSPLIT>
__global__ __launch_bounds__(256)
void hgemm(const _Float16* __restrict__ A, int lda,
           const _Float16* __restrict__ Bt, int ldb,
           const float* __restrict__ bias,
           float* __restrict__ C, _Float16* __restrict__ Ch,
           size_t cslice, int N, int K) {
  constexpr int BM = 128;
  constexpr int FM = BM / 16 / WGM;
  constexpr int FN = BN / 16 / WGN;
  __shared__ _Float16 sA[BM * 32];
  __shared__ _Float16 sB[BN * 32];
  const int tid = threadIdx.x;
  const int ln  = tid & 63;
  const int wid = tid >> 6;
  const int wm  = wid % WGM;
  const int wn  = wid / WGM;
  const int m0  = blockIdx.y * BM;
  const int n0  = blockIdx.x * BN;
  const int l15 = ln & 15;
  const int q   = ln >> 4;

  const int kLen = K / KSPLIT;
  const int kbeg = blockIdx.z * kLen;
  if (KSPLIT > 1) C += (size_t)blockIdx.z * cslice;

  floatx4 acc[FM][FN];
  #pragma unroll
  for (int i = 0; i < FM; ++i)
    #pragma unroll
    for (int j = 0; j < FN; ++j)
      acc[i][j] = floatx4{0.f, 0.f, 0.f, 0.f};

  for (int k0 = kbeg; k0 < kbeg + kLen; k0 += 32) {
    __syncthreads();
    #pragma unroll
    for (int s = 0; s < (BM * 4 + 255) / 256; ++s) {
      const int i = s * 256 + tid;
      if (BM * 4 % 256 == 0 || i < BM * 4) {
        const int m = i >> 2;
        const int cg = (i & 3) ^ ((m >> 1) & 3);
        gload_lds16(A + (size_t)(m0 + m) * lda + k0 + cg * 8, sA + i * 8);
      }
    }
    #pragma unroll
    for (int s = 0; s < (BN * 4 + 255) / 256; ++s) {
      const int i = s * 256 + tid;
      if (BN * 4 % 256 == 0 || i < BN * 4) {
        const int n = i >> 2;
        const int cg = (i & 3) ^ ((n >> 1) & 3);
        gload_lds16(Bt + (size_t)(n0 + n) * ldb + k0 + cg * 8, sB + i * 8);
      }
    }
    __syncthreads();

    half8 af[FM], bf[FN];
    #pragma unroll
    for (int fm = 0; fm < FM; ++fm) {
      const int mr = wm * FM * 16 + fm * 16 + l15;
      const int cl = q ^ ((mr >> 1) & 3);
      af[fm] = *(const half8*)(sA + mr * 32 + cl * 8);
    }
    #pragma unroll
    for (int fn = 0; fn < FN; ++fn) {
      const int nr = wn * FN * 16 + fn * 16 + l15;
      const int cl = q ^ ((nr >> 1) & 3);
      bf[fn] = *(const half8*)(sB + nr * 32 + cl * 8);
    }
    #pragma unroll
    for (int fm = 0; fm < FM; ++fm)
      #pragma unroll
      for (int fn = 0; fn < FN; ++fn)
        acc[fm][fn] = __builtin_amdgcn_mfma_f32_16x16x32_f16(
            af[fm], bf[fn], acc[fm][fn], 0, 0, 0);
  }

  // C/D layout: col = lane&15, row = (lane>>4)*4 + reg  (m89/m91 verified)
  #pragma unroll
  for (int fm = 0; fm < FM; ++fm) {
    #pragma unroll
    for (int fn = 0; fn < FN; ++fn) {
      const int col = n0 + wn * FN * 16 + fn * 16 + l15;
      #pragma unroll
      for (int r = 0; r < 4; ++r) {
        const int row = m0 + wm * FM * 16 + fm * 16 + q * 4 + r;
        float v = acc[fm][fn][r];
        if (EPI == 2) {
          if (col < ED) C[(size_t)row * ED + col] = v;
          else          Ch[(size_t)row * ED + (col - ED)] = (_Float16)silu_f(v);
        } else if (EPI == 3) {
          v += bias[col];
          v = fmaxf(v, 0.f) + log1pf(__expf(-fabsf(v)));  // stable softplus
          C[(size_t)row * N + col] = v;
        } else {
          C[(size_t)row * N + col] = v;
        }
      }
    }
  }
}

// ---------------------------------------------------------------------------
// Fused prep: x fp32->fp16 + 4 transpose-converts, dispatched by block range.
// ---------------------------------------------------------------------------
__device__ __forceinline__ void transpose_tile(const float* __restrict__ src,
                                               _Float16* __restrict__ dst,
                                               int R, int C, int bx, int by,
                                               int tid) {
  __shared__ float t[32][33];
  const int tx = tid & 31, ty = tid >> 5;
  const int c0 = bx * 32, r0 = by * 32;
  #pragma unroll
  for (int s = 0; s < 4; ++s)
    t[ty + s * 8][tx] = src[(size_t)(r0 + ty + s * 8) * C + c0 + tx];
  __syncthreads();
  #pragma unroll
  for (int s = 0; s < 4; ++s)
    dst[(size_t)(c0 + ty + s * 8) * R + r0 + tx] = (_Float16)t[tx][ty + s * 8];
}

// block ranges: [0,4096) cvt x | [4096,8192) Win^T | [8192,10240) Wout^T
//               [10240,10432) Wx^T | [10432,10560) Wdt^T
#define PREP_BLOCKS 10560
__global__ __launch_bounds__(256)
void prep_kernel(const float* __restrict__ x, _Float16* __restrict__ x_h,
                 const float* __restrict__ Win, _Float16* __restrict__ Wint,
                 const float* __restrict__ Wout, _Float16* __restrict__ Woutt,
                 const float* __restrict__ Wx, _Float16* __restrict__ Wxt,
                 const float* __restrict__ Wdt, _Float16* __restrict__ Wdtt) {
  const int bid = blockIdx.x, tid = threadIdx.x;
  if (bid < 4096) {
    const int i = bid * 1024 + tid * 4;
    const float4 v = *(const float4*)(x + i);
    half4 o;
    o[0] = (_Float16)v.x; o[1] = (_Float16)v.y;
    o[2] = (_Float16)v.z; o[3] = (_Float16)v.w;
    *(half4*)(x_h + i) = o;
  } else if (bid < 8192) {
    const int t = bid - 4096;            // Win: 1024 x 4096 -> 4096 x 1024
    transpose_tile(Win, Wint, DM, 2 * ED, t & 127, t >> 7, tid);
  } else if (bid < 10240) {
    const int t = bid - 8192;            // Wout: 2048 x 1024 -> 1024 x 2048
    transpose_tile(Wout, Woutt, ED, DM, t & 31, t >> 5, tid);
  } else if (bid < 10432) {
    const int t = bid - 10240;           // Wx: 2048 x 96 -> 96 x 2048
    transpose_tile(Wx, Wxt, ED, 96, t % 3, t / 3, tid);
  } else {
    const int t = bid - 10432;           // Wdt: 64 x 2048 -> 2048 x 64
    transpose_tile(Wdt, Wdtt, DR, ED, t & 63, t >> 6, tid);
  }
}

// Causal depthwise conv (width 4) + bias + silu -> u_h fp16 only (for xproj).
__global__ __launch_bounds__(256)
void conv_silu_kernel(const float* __restrict__ xb, const float* __restrict__ w,
                      const float* __restrict__ cb, _Float16* __restrict__ u_h) {
  const int idx = blockIdx.x * 256 + threadIdx.x;   // (b*SEQ+t)*ED + d
  const int d = idx & (ED - 1);
  const int t = (idx >> 11) & (SEQ - 1);
  const float4 wv = ((const float4*)w)[d];
  const float* base = xb + (size_t)(idx >> 11) * ED + d;
  float acc = cb[d];
  acc = fmaf(wv.w, base[0], acc);
  if (t >= 1) acc = fmaf(wv.z, base[-ED], acc);
  if (t >= 2) acc = fmaf(wv.y, base[-2 * ED], acc);
  if (t >= 3) acc = fmaf(wv.x, base[-3 * ED], acc);
  u_h[idx] = (_Float16)silu_f(acc);
}

// reduce split-K partials -> dbc fp32; also emit fp16 copy of the dt-rank
// slice (first 64 cols) packed as (NROWS x 64) for the dt hgemm.
__global__ __launch_bounds__(256)
void xproj_reduce(const float* __restrict__ part, float* __restrict__ dbc,
                  _Float16* __restrict__ dbc64h) {
  const int idx = blockIdx.x * 256 + threadIdx.x;  // < NROWS*96
  float s = 0.f;
  #pragma unroll
  for (int r = 0; r < 8; ++r) s += part[(size_t)r * NROWS * 96 + idx];
  dbc[idx] = s;
  const int col = idx % 96;
  if (col < DR) dbc64h[(idx / 96) * DR + col] = (_Float16)s;
}

// ---------------------------------------------------------------------------
// Channel-per-lane chunked scan with inline conv recompute.
// Thread = (d, b, chunk g); 16 states in registers; dt/xb loads coalesced
// (lane = d); B/C wave-uniform; n-reduction in-register.
// u is recomputed from xb via the rolling 4-tap conv (fp32, exact).
// ---------------------------------------------------------------------------
__device__ __forceinline__ void conv_init(const float* xbp, int tg0,
                                          float& x1, float& x2, float& x3) {
  // xbp points at (row0, d); rows row0-1.. are valid when tg0 >= k
  x1 = (tg0 >= 1) ? xbp[-(int)ED] : 0.f;
  x2 = (tg0 >= 2) ? xbp[-2 * (int)ED] : 0.f;
  x3 = (tg0 >= 3) ? xbp[-3 * (int)ED] : 0.f;
}

__global__ __launch_bounds__(256)
void scan2_summary(const float* __restrict__ dt, const float* __restrict__ xb,
                   const float* __restrict__ convw, const float* __restrict__ convb,
                   const float* __restrict__ dbc, const float* __restrict__ A_log,
                   float* __restrict__ Pbuf, float* __restrict__ Sbuf) {
  const int d = blockIdx.x * 256 + threadIdx.x;   // grid.x = ED/256
  const int b = blockIdx.y;
  const int g = blockIdx.z;

  float Adn[16];
  {
    const float4* al = (const float4*)(A_log + (size_t)d * NS);
    #pragma unroll
    for (int i = 0; i < 4; ++i) {
      const float4 v = al[i];
      Adn[i * 4 + 0] = -__expf(v.x); Adn[i * 4 + 1] = -__expf(v.y);
      Adn[i * 4 + 2] = -__expf(v.z); Adn[i * 4 + 3] = -__expf(v.w);
    }
  }
  const float4 wv = ((const float4*)convw)[d];
  const float cbd = convb[d];

  float P[16], S[16];
  #pragma unroll
  for (int n = 0; n < 16; ++n) { P[n] = 1.f; S[n] = 0.f; }

  const int tg0 = g * CLEN;
  const size_t row0 = (size_t)b * SEQ + tg0;
  const float* dtp = dt + row0 * ED + d;
  const float* xbp = xb + row0 * ED + d;
  float x1, x2, x3;
  conv_init(xbp, tg0, x1, x2, x3);

  for (int t = 0; t < CLEN; ++t) {
    const float xt  = xbp[(size_t)t * ED];
    const float dti = dtp[(size_t)t * ED];
    float cv = cbd;
    cv = fmaf(wv.w, xt, cv);
    cv = fmaf(wv.z, x1, cv);
    cv = fmaf(wv.y, x2, cv);
    cv = fmaf(wv.x, x3, cv);
    const float ui = silu_f(cv);
    x3 = x2; x2 = x1; x1 = xt;

    const float4* bc = (const float4*)(dbc + (row0 + t) * 96 + DR);  // uniform
    float Bv[16];
    #pragma unroll
    for (int i = 0; i < 4; ++i) {
      const float4 v = bc[i];
      Bv[i * 4 + 0] = v.x; Bv[i * 4 + 1] = v.y;
      Bv[i * 4 + 2] = v.z; Bv[i * 4 + 3] = v.w;
    }
    const float dtu = dti * ui;
    #pragma unroll
    for (int n = 0; n < 16; ++n) {
      const float a = __expf(dti * Adn[n]);
      S[n] = fmaf(S[n], a, dtu * Bv[n]);
      P[n] *= a;
    }
  }
  const size_t c0 = (size_t)g * CSTATES + ((size_t)(b * ED + d)) * NS;
  #pragma unroll
  for (int i = 0; i < 4; ++i) {
    *(float4*)(Pbuf + c0 + i * 4) = float4{P[i*4], P[i*4+1], P[i*4+2], P[i*4+3]};
    *(float4*)(Sbuf + c0 + i * 4) = float4{S[i*4], S[i*4+1], S[i*4+2], S[i*4+3]};
  }
}

// Compose chunk summaries -> each chunk's ENTRY state h0 (in-place over Pbuf).
__global__ __launch_bounds__(256)
void scan2_compose(float* __restrict__ Pbuf, const float* __restrict__ Sbuf) {
  const unsigned c = blockIdx.x * 256 + threadIdx.x;  // < CSTATES
  float h = 0.f;
  for (int g = 0; g < NCHUNK; ++g) {
    const size_t idx = (size_t)g * CSTATES + c;
    const float p = Pbuf[idx], s = Sbuf[idx];
    Pbuf[idx] = h;
    h = fmaf(p, h, s);
  }
}

// Final pass: recurrence from h0; fused gate y_h = (fp16)(y * silu_res),
// written IN-PLACE over resh (same element, same thread, read-before-write).
__global__ __launch_bounds__(256)
void scan2_apply(const float* __restrict__ dt, const float* __restrict__ xb,
                 const float* __restrict__ convw, const float* __restrict__ convb,
                 const float* __restrict__ dbc, const float* __restrict__ A_log,
                 const float* __restrict__ Dp, const float* __restrict__ Pbuf,
                 _Float16* __restrict__ resh) {
  const int d = blockIdx.x * 256 + threadIdx.x;
  const int b = blockIdx.y;
  const int g = blockIdx.z;

  float Adn[16];
  {
    const float4* al = (const float4*)(A_log + (size_t)d * NS);
    #pragma unroll
    for (int i = 0; i < 4; ++i) {
      const float4 v = al[i];
      Adn[i * 4 + 0] = -__expf(v.x); Adn[i * 4 + 1] = -__expf(v.y);
      Adn[i * 4 + 2] = -__expf(v.z); Adn[i * 4 + 3] = -__expf(v.w);
    }
  }
  const float4 wv = ((const float4*)convw)[d];
  const float cbd = convb[d];
  const float Dd = Dp[d];

  float h[16];
  const size_t c0 = (size_t)g * CSTATES + ((size_t)(b * ED + d)) * NS;
  #pragma unroll
  for (int i = 0; i < 4; ++i) {
    const float4 v = *(const float4*)(Pbuf + c0 + i * 4);
    h[i * 4 + 0] = v.x; h[i * 4 + 1] = v.y;
    h[i * 4 + 2] = v.z; h[i * 4 + 3] = v.w;
  }

  const int tg0 = g * CLEN;
  const size_t row0 = (size_t)b * SEQ + tg0;
  const float* dtp = dt + row0 * ED + d;
  const float* xbp = xb + row0 * ED + d;
  _Float16* rp = resh + row0 * ED + d;
  float x1, x2, x3;
  conv_init(xbp, tg0, x1, x2, x3);

  for (int t = 0; t < CLEN; ++t) {
    const float xt  = xbp[(size_t)t * ED];
    const float dti = dtp[(size_t)t * ED];
    float cv = cbd;
    cv = fmaf(wv.w, xt, cv);
    cv = fmaf(wv.z, x1, cv);
    cv = fmaf(wv.y, x2, cv);
    cv = fmaf(wv.x, x3, cv);
    const float ui = silu_f(cv);
    x3 = x2; x2 = x1; x1 = xt;

    const float4* bc = (const float4*)(dbc + (row0 + t) * 96 + DR);  // uniform
    float Bv[16], Cv[16];
    #pragma unroll
    for (int i = 0; i < 4; ++i) {
      const float4 v = bc[i];
      Bv[i * 4 + 0] = v.x; Bv[i * 4 + 1] = v.y;
      Bv[i * 4 + 2] = v.z; Bv[i * 4 + 3] = v.w;
      const float4 w = bc[4 + i];
      Cv[i * 4 + 0] = w.x; Cv[i * 4 + 1] = w.y;
      Cv[i * 4 + 2] = w.z; Cv[i * 4 + 3] = w.w;
    }
    const float dtu = dti * ui;
    float y = Dd * ui;
    #pragma unroll
    for (int n = 0; n < 16; ++n) {
      const float a = __expf(dti * Adn[n]);
      h[n] = fmaf(h[n], a, dtu * Bv[n]);
      y = fmaf(h[n], Cv[n], y);
    }
    const float sres = (float)rp[(size_t)t * ED];   // silu(res), read before write
    rp[(size_t)t * ED] = (_Float16)(y * sres);      // y_h in-place
  }
}

extern "C" void kernel_launch(void* const* d_in, const int* in_sizes, int n_in,
                              void* d_out, int out_size, void* d_ws, size_t ws_size,
                              hipStream_t stream) {
  (void)in_sizes; (void)n_in; (void)out_size; (void)ws_size;
  const float* x     = (const float*)d_in[0];
  const float* Win   = (const float*)d_in[1];
  const float* convw = (const float*)d_in[2];
  const float* convb = (const float*)d_in[3];
  const float* Wx    = (const float*)d_in[4];
  const float* Wdt   = (const float*)d_in[5];
  const float* bdt   = (const float*)d_in[6];
  const float* Alog  = (const float*)d_in[7];
  const float* Dp    = (const float*)d_in[8];
  const float* Wout  = (const float*)d_in[9];

  float* ws   = (float*)d_ws;
  float* xb   = ws + OFF_XB;
  _Float16* resh = (_Float16*)(ws + OFF_RESH);
  float* Pbuf = ws + OFF_PS;                           // 4,194,304 f
  float* Sbuf = ws + OFF_PS + 4194304;                 // 4,194,304 f
  float* dt   = ws + OFF_DT;
  float* dbc  = ws + OFF_DBC;
  float* part = ws + OFF_PART;
  _Float16* Woutt  = (_Float16*)(part + 4194304);      // 2M halves
  _Float16* Wxt    = (_Float16*)(part + 5242880);      // 192K halves
  _Float16* dbc64h = (_Float16*)(part + 5341184);      // 256K halves
  _Float16* Wdtt   = (_Float16*)(part + 5472256);      // 128K halves
  float* out  = (float*)d_out;

  _Float16* x_h  = (_Float16*)(ws + OFF_DT);           // 4M halves (staging)
  _Float16* Wint = (_Float16*)(ws + OFF_DT + 2097152); // 4M halves (staging)
  _Float16* u_h  = (_Float16*)(ws + OFF_DT + 4194304); // 8.4M halves (staging)

  // 0) fused prep: cvt x + transpose-convert Win/Wout/Wx/Wdt
  prep_kernel<<<PREP_BLOCKS, 256, 0, stream>>>(
      x, x_h, Win, Wint, Wout, Woutt, Wx, Wxt, Wdt, Wdtt);
  // 1) in_proj: xb fp32 + resh = (fp16)silu(res), split epilogue
  hgemm<128, 2, 2, 2, 1><<<dim3((2 * ED) / 128, NROWS / 128), 256, 0, stream>>>(
      x_h, DM, Wint, DM, nullptr, xb, resh, 0, 2 * ED, DM);
  // 2) u_h = (fp16)silu(causal_dwconv(xb) + conv_b)
  conv_silu_kernel<<<(NROWS * ED) / 256, 256, 0, stream>>>(xb, convw, convb, u_h);
  // 3) dbc = u @ x_proj_w  (MFMA, split-K=8 + reduce; reduce emits dbc64h fp16)
  hgemm<96, 4, 1, 0, 8><<<dim3(1, NROWS / 128, 8), 256, 0, stream>>>(
      u_h, ED, Wxt, ED, nullptr, part, nullptr, (size_t)NROWS * 96, 96, ED);
  xproj_reduce<<<(NROWS * 96) / 256, 256, 0, stream>>>(part, dbc, dbc64h);
  // 4) dt = softplus(dbc64 @ dt_proj_w + b)  (MFMA K=64; overwrites staging)
  hgemm<128, 2, 2, 3, 1><<<dim3(ED / 128, NROWS / 128), 256, 0, stream>>>(
      dbc64h, DR, Wdtt, DR, bdt, dt, nullptr, 0, ED, DR);
  // 5) chunked scan, channel-per-lane, conv recomputed inline from xb
  scan2_summary<<<dim3(ED / 256, BATCH, NCHUNK), 256, 0, stream>>>(
      dt, xb, convw, convb, dbc, Alog, Pbuf, Sbuf);
  scan2_compose<<<CSTATES / 256, 256, 0, stream>>>(Pbuf, Sbuf);
  scan2_apply<<<dim3(ED / 256, BATCH, NCHUNK), 256, 0, stream>>>(
      dt, xb, convw, convb, dbc, Alog, Dp, Pbuf, resh);
  // 6) out = y_h @ out_proj_w  (MFMA)
  hgemm<64, 4, 1, 0, 1><<<dim3(DM / 64, NROWS / 128), 256, 0, stream>>>(
      resh, ED, Woutt, ED, nullptr, out, nullptr, 0, DM, ED);
}

// Round 6
// 351.204 us; speedup vs baseline: 4.3863x; 1.0377x over previous
//
#include <hip/hip_runtime.h>
#include <cstddef>
#include <cstdint>

// Problem constants
#define BATCH 2
#define SEQ   2048
#define DM    1024   // d_model
#define ED    2048   // d_inner
#define NS    16     // d_state
#define DR    64     // dt_rank
#define NROWS (BATCH*SEQ)  // 4096

// Chunked-scan parameters: SEQ = NCHUNK * CLEN
#define NCHUNK 64
#define CLEN   32
#define CSTATES (BATCH*ED*NS)   // 65536 independent recurrences

// ---------------------------------------------------------------------------
// workspace layout (float offsets), total <= 37,093,376 floats = 148.4 MB
// ---------------------------------------------------------------------------
#define OFF_XBH   ((size_t)0)          // 4,194,304 f  (B,L,ED) fp16 conv input
#define OFF_RESH  ((size_t)4194304)    // 4,194,304 f  (B,L,ED) fp16 silu(res); apply overwrites with y_h
#define OFF_PS    ((size_t)8388608)    // 8,388,608 f  P (4,194,304) + S (4,194,304)
#define OFF_DT    ((size_t)16777216)   // 8,388,608 f  region:
//   dth  @ OFF_DT            : 8.4M halves (4,194,304 f) — overwrites x_h/Wint (dead)
//   x_h  @ OFF_DT            : 4M halves  (staging, dead after in_proj)
//   Wint @ OFF_DT+2,097,152  : 4M halves  (staging, dead after in_proj)
//   u_h  @ OFF_DT+4,194,304  : 8.4M halves (staging, dead after xproj)
#define OFF_DBC   ((size_t)25165824)   //   393,216 f  (B,L,96) fp32
#define OFF_PART  ((size_t)25559040)   // partials 3,145,728 | Woutt 1,048,576 |
                                       // Wxt 98,304 | dbc64h 131,072 | Wdtt 65,536

typedef _Float16 half8 __attribute__((ext_vector_type(8)));
typedef _Float16 half4 __attribute__((ext_vector_type(4)));
typedef float    floatx4 __attribute__((ext_vector_type(4)));

__device__ __forceinline__ float silu_f(float x) { return x / (1.f + __expf(-x)); }

__device__ __forceinline__ void gload_lds16(const _Float16* g, _Float16* l) {
  __builtin_amdgcn_global_load_lds(
      (const __attribute__((address_space(1))) void*)g,
      (__attribute__((address_space(3))) void*)l, 16, 0, 0);
}

// ---------------------------------------------------------------------------
// fp16 MFMA GEMM: C(MxN) = A(MxK fp16 rm, lda) @ Bt^T (Bt[n][k] fp16, ldb).
// BM=128, BK template (32/64), 256 threads (4 waves, WGM x WGN), 16x16x32 MFMA.
// LDS: [row][chunk16B] with XOR swizzle c_l = c_g ^ ((row>>1)&(CPR-1)):
// keeps global_load_lds lane order; frag ds_read_b128 lands as a free 2-way
// bank alias (each chunk hit by exactly 2 of 16 lanes).
// EPI 0: fp32 store to C.
// EPI 2: col<ED -> Ch=(fp16)v; col>=ED -> Ch2=(fp16)silu(v) (both stride ED).
// EPI 3: Ch = (fp16)softplus(v + bias[col])  (dt_proj).
// KSPLIT: blockIdx.z slices K; C += z*cslice.
// ---------------------------------------------------------------------------
template<int BN, int WGM, int WGN, int EPI, int KSPLIT, int BK>
__global__ __launch_bounds__(256)
void hgemm(const _Float16* __restrict__ A, int lda,
           const _Float16* __restrict__ Bt, int ldb,
           const float* __restrict__ bias,
           float* __restrict__ C, _Float16* __restrict__ Ch,
           _Float16* __restrict__ Ch2,
           size_t cslice, int N, int K) {
  constexpr int BM = 128;
  constexpr int FM = BM / 16 / WGM;
  constexpr int FN = BN / 16 / WGN;
  constexpr int CPR = BK / 8;          // 16B chunks per row
  __shared__ _Float16 sA[BM * BK];
  __shared__ _Float16 sB[BN * BK];
  const int tid = threadIdx.x;
  const int ln  = tid & 63;
  const int wid = tid >> 6;
  const int wm  = wid % WGM;
  const int wn  = wid / WGM;
  const int m0  = blockIdx.y * BM;
  const int n0  = blockIdx.x * BN;
  const int l15 = ln & 15;
  const int q   = ln >> 4;

  const int kLen = K / KSPLIT;
  const int kbeg = blockIdx.z * kLen;
  if (KSPLIT > 1) C += (size_t)blockIdx.z * cslice;

  floatx4 acc[FM][FN];
  #pragma unroll
  for (int i = 0; i < FM; ++i)
    #pragma unroll
    for (int j = 0; j < FN; ++j)
      acc[i][j] = floatx4{0.f, 0.f, 0.f, 0.f};

  for (int k0 = kbeg; k0 < kbeg + kLen; k0 += BK) {
    __syncthreads();
    #pragma unroll
    for (int s = 0; s < (BM * CPR) / 256; ++s) {
      const int i = s * 256 + tid;
      const int m = i / CPR;
      const int cg = (i & (CPR - 1)) ^ ((m >> 1) & (CPR - 1));
      gload_lds16(A + (size_t)(m0 + m) * lda + k0 + cg * 8, sA + i * 8);
    }
    #pragma unroll
    for (int s = 0; s < (BN * CPR) / 256; ++s) {
      const int i = s * 256 + tid;
      const int n = i / CPR;
      const int cg = (i & (CPR - 1)) ^ ((n >> 1) & (CPR - 1));
      gload_lds16(Bt + (size_t)(n0 + n) * ldb + k0 + cg * 8, sB + i * 8);
    }
    __syncthreads();

    #pragma unroll
    for (int h = 0; h < BK / 32; ++h) {
      half8 af[FM], bf[FN];
      #pragma unroll
      for (int fm = 0; fm < FM; ++fm) {
        const int mr = wm * FM * 16 + fm * 16 + l15;
        const int cl = (h * 4 + q) ^ ((mr >> 1) & (CPR - 1));
        af[fm] = *(const half8*)(sA + mr * BK + cl * 8);
      }
      #pragma unroll
      for (int fn = 0; fn < FN; ++fn) {
        const int nr = wn * FN * 16 + fn * 16 + l15;
        const int cl = (h * 4 + q) ^ ((nr >> 1) & (CPR - 1));
        bf[fn] = *(const half8*)(sB + nr * BK + cl * 8);
      }
      #pragma unroll
      for (int fm = 0; fm < FM; ++fm)
        #pragma unroll
        for (int fn = 0; fn < FN; ++fn)
          acc[fm][fn] = __builtin_amdgcn_mfma_f32_16x16x32_f16(
              af[fm], bf[fn], acc[fm][fn], 0, 0, 0);
    }
  }

  // C/D layout: col = lane&15, row = (lane>>4)*4 + reg  (m89/m91 verified)
  #pragma unroll
  for (int fm = 0; fm < FM; ++fm) {
    #pragma unroll
    for (int fn = 0; fn < FN; ++fn) {
      const int col = n0 + wn * FN * 16 + fn * 16 + l15;
      #pragma unroll
      for (int r = 0; r < 4; ++r) {
        const int row = m0 + wm * FM * 16 + fm * 16 + q * 4 + r;
        float v = acc[fm][fn][r];
        if (EPI == 2) {
          if (col < ED) Ch[(size_t)row * ED + col] = (_Float16)v;
          else          Ch2[(size_t)row * ED + (col - ED)] = (_Float16)silu_f(v);
        } else if (EPI == 3) {
          v += bias[col];
          v = fmaxf(v, 0.f) + log1pf(__expf(-fabsf(v)));  // stable softplus
          Ch[(size_t)row * N + col] = (_Float16)v;
        } else {
          C[(size_t)row * N + col] = v;
        }
      }
    }
  }
}

// ---------------------------------------------------------------------------
// Fused prep: x fp32->fp16 + 4 transpose-converts, dispatched by block range.
// ---------------------------------------------------------------------------
__device__ __forceinline__ void transpose_tile(const float* __restrict__ src,
                                               _Float16* __restrict__ dst,
                                               int R, int C, int bx, int by,
                                               int tid) {
  __shared__ float t[32][33];
  const int tx = tid & 31, ty = tid >> 5;
  const int c0 = bx * 32, r0 = by * 32;
  #pragma unroll
  for (int s = 0; s < 4; ++s)
    t[ty + s * 8][tx] = src[(size_t)(r0 + ty + s * 8) * C + c0 + tx];
  __syncthreads();
  #pragma unroll
  for (int s = 0; s < 4; ++s)
    dst[(size_t)(c0 + ty + s * 8) * R + r0 + tx] = (_Float16)t[tx][ty + s * 8];
}

// block ranges: [0,4096) cvt x | [4096,8192) Win^T | [8192,10240) Wout^T
//               [10240,10432) Wx^T | [10432,10560) Wdt^T
#define PREP_BLOCKS 10560
__global__ __launch_bounds__(256)
void prep_kernel(const float* __restrict__ x, _Float16* __restrict__ x_h,
                 const float* __restrict__ Win, _Float16* __restrict__ Wint,
                 const float* __restrict__ Wout, _Float16* __restrict__ Woutt,
                 const float* __restrict__ Wx, _Float16* __restrict__ Wxt,
                 const float* __restrict__ Wdt, _Float16* __restrict__ Wdtt) {
  const int bid = blockIdx.x, tid = threadIdx.x;
  if (bid < 4096) {
    const int i = bid * 1024 + tid * 4;
    const float4 v = *(const float4*)(x + i);
    half4 o;
    o[0] = (_Float16)v.x; o[1] = (_Float16)v.y;
    o[2] = (_Float16)v.z; o[3] = (_Float16)v.w;
    *(half4*)(x_h + i) = o;
  } else if (bid < 8192) {
    const int t = bid - 4096;            // Win: 1024 x 4096 -> 4096 x 1024
    transpose_tile(Win, Wint, DM, 2 * ED, t & 127, t >> 7, tid);
  } else if (bid < 10240) {
    const int t = bid - 8192;            // Wout: 2048 x 1024 -> 1024 x 2048
    transpose_tile(Wout, Woutt, ED, DM, t & 31, t >> 5, tid);
  } else if (bid < 10432) {
    const int t = bid - 10240;           // Wx: 2048 x 96 -> 96 x 2048
    transpose_tile(Wx, Wxt, ED, 96, t % 3, t / 3, tid);
  } else {
    const int t = bid - 10432;           // Wdt: 64 x 2048 -> 2048 x 64
    transpose_tile(Wdt, Wdtt, DR, ED, t & 63, t >> 6, tid);
  }
}

// Causal depthwise conv (width 4) + bias + silu -> u_h fp16 (xproj input).
__global__ __launch_bounds__(256)
void conv_silu_kernel(const _Float16* __restrict__ xbh, const float* __restrict__ w,
                      const float* __restrict__ cb, _Float16* __restrict__ u_h) {
  const int idx = blockIdx.x * 256 + threadIdx.x;   // (b*SEQ+t)*ED + d
  const int d = idx & (ED - 1);
  const int t = (idx >> 11) & (SEQ - 1);
  const float4 wv = ((const float4*)w)[d];
  const _Float16* base = xbh + (size_t)(idx >> 11) * ED + d;
  float acc = cb[d];
  acc = fmaf(wv.w, (float)base[0], acc);
  if (t >= 1) acc = fmaf(wv.z, (float)base[-ED], acc);
  if (t >= 2) acc = fmaf(wv.y, (float)base[-2 * ED], acc);
  if (t >= 3) acc = fmaf(wv.x, (float)base[-3 * ED], acc);
  u_h[idx] = (_Float16)silu_f(acc);
}

// reduce split-K partials -> dbc fp32; also emit fp16 dt-rank slice packed
// as (NROWS x 64) for the dt hgemm.
__global__ __launch_bounds__(256)
void xproj_reduce(const float* __restrict__ part, float* __restrict__ dbc,
                  _Float16* __restrict__ dbc64h) {
  const int idx = blockIdx.x * 256 + threadIdx.x;  // < NROWS*96
  float s = 0.f;
  #pragma unroll
  for (int r = 0; r < 8; ++r) s += part[(size_t)r * NROWS * 96 + idx];
  dbc[idx] = s;
  const int col = idx % 96;
  if (col < DR) dbc64h[(idx / 96) * DR + col] = (_Float16)s;
}

// ---------------------------------------------------------------------------
// Channel-per-lane chunked scan with inline conv recompute (fp16 xb/dt in,
// fp32 state). Thread = (d, b, chunk g); 16 states in registers; dt/xb loads
// coalesced (lane = d); B/C wave-uniform; n-reduction in-register.
// ---------------------------------------------------------------------------
__device__ __forceinline__ void conv_init_h(const _Float16* xbp, int tg0,
                                            float& x1, float& x2, float& x3) {
  x1 = (tg0 >= 1) ? (float)xbp[-(int)ED] : 0.f;
  x2 = (tg0 >= 2) ? (float)xbp[-2 * (int)ED] : 0.f;
  x3 = (tg0 >= 3) ? (float)xbp[-3 * (int)ED] : 0.f;
}

__global__ __launch_bounds__(256)
void scan2_summary(const _Float16* __restrict__ dth, const _Float16* __restrict__ xbh,
                   const float* __restrict__ convw, const float* __restrict__ convb,
                   const float* __restrict__ dbc, const float* __restrict__ A_log,
                   float* __restrict__ Pbuf, float* __restrict__ Sbuf) {
  const int d = blockIdx.x * 256 + threadIdx.x;   // grid.x = ED/256
  const int b = blockIdx.y;
  const int g = blockIdx.z;

  float Adn[16];
  {
    const float4* al = (const float4*)(A_log + (size_t)d * NS);
    #pragma unroll
    for (int i = 0; i < 4; ++i) {
      const float4 v = al[i];
      Adn[i * 4 + 0] = -__expf(v.x); Adn[i * 4 + 1] = -__expf(v.y);
      Adn[i * 4 + 2] = -__expf(v.z); Adn[i * 4 + 3] = -__expf(v.w);
    }
  }
  const float4 wv = ((const float4*)convw)[d];
  const float cbd = convb[d];

  float P[16], S[16];
  #pragma unroll
  for (int n = 0; n < 16; ++n) { P[n] = 1.f; S[n] = 0.f; }

  const int tg0 = g * CLEN;
  const size_t row0 = (size_t)b * SEQ + tg0;
  const _Float16* dtp = dth + row0 * ED + d;
  const _Float16* xbp = xbh + row0 * ED + d;
  float x1, x2, x3;
  conv_init_h(xbp, tg0, x1, x2, x3);

  for (int t = 0; t < CLEN; ++t) {
    const float xt  = (float)xbp[(size_t)t * ED];
    const float dti = (float)dtp[(size_t)t * ED];
    float cv = cbd;
    cv = fmaf(wv.w, xt, cv);
    cv = fmaf(wv.z, x1, cv);
    cv = fmaf(wv.y, x2, cv);
    cv = fmaf(wv.x, x3, cv);
    const float ui = silu_f(cv);
    x3 = x2; x2 = x1; x1 = xt;

    const float4* bc = (const float4*)(dbc + (row0 + t) * 96 + DR);  // uniform
    float Bv[16];
    #pragma unroll
    for (int i = 0; i < 4; ++i) {
      const float4 v = bc[i];
      Bv[i * 4 + 0] = v.x; Bv[i * 4 + 1] = v.y;
      Bv[i * 4 + 2] = v.z; Bv[i * 4 + 3] = v.w;
    }
    const float dtu = dti * ui;
    #pragma unroll
    for (int n = 0; n < 16; ++n) {
      const float a = __expf(dti * Adn[n]);
      S[n] = fmaf(S[n], a, dtu * Bv[n]);
      P[n] *= a;
    }
  }
  const size_t c0 = (size_t)g * CSTATES + ((size_t)(b * ED + d)) * NS;
  #pragma unroll
  for (int i = 0; i < 4; ++i) {
    *(float4*)(Pbuf + c0 + i * 4) = float4{P[i*4], P[i*4+1], P[i*4+2], P[i*4+3]};
    *(float4*)(Sbuf + c0 + i * 4) = float4{S[i*4], S[i*4+1], S[i*4+2], S[i*4+3]};
  }
}

// Compose chunk summaries -> each chunk's ENTRY state h0 (in-place over Pbuf).
__global__ __launch_bounds__(256)
void scan2_compose(float* __restrict__ Pbuf, const float* __restrict__ Sbuf) {
  const unsigned c = blockIdx.x * 256 + threadIdx.x;  // < CSTATES
  float h = 0.f;
  for (int g = 0; g < NCHUNK; ++g) {
    const size_t idx = (size_t)g * CSTATES + c;
    const float p = Pbuf[idx], s = Sbuf[idx];
    Pbuf[idx] = h;
    h = fmaf(p, h, s);
  }
}

// Final pass: recurrence from h0; fused gate y_h = (fp16)(y * silu_res),
// written IN-PLACE over resh (same element, same thread, read-before-write).
__global__ __launch_bounds__(256)
void scan2_apply(const _Float16* __restrict__ dth, const _Float16* __restrict__ xbh,
                 const float* __restrict__ convw, const float* __restrict__ convb,
                 const float* __restrict__ dbc, const float* __restrict__ A_log,
                 const float* __restrict__ Dp, const float* __restrict__ Pbuf,
                 _Float16* __restrict__ resh) {
  const int d = blockIdx.x * 256 + threadIdx.x;
  const int b = blockIdx.y;
  const int g = blockIdx.z;

  float Adn[16];
  {
    const float4* al = (const float4*)(A_log + (size_t)d * NS);
    #pragma unroll
    for (int i = 0; i < 4; ++i) {
      const float4 v = al[i];
      Adn[i * 4 + 0] = -__expf(v.x); Adn[i * 4 + 1] = -__expf(v.y);
      Adn[i * 4 + 2] = -__expf(v.z); Adn[i * 4 + 3] = -__expf(v.w);
    }
  }
  const float4 wv = ((const float4*)convw)[d];
  const float cbd = convb[d];
  const float Dd = Dp[d];

  float h[16];
  const size_t c0 = (size_t)g * CSTATES + ((size_t)(b * ED + d)) * NS;
  #pragma unroll
  for (int i = 0; i < 4; ++i) {
    const float4 v = *(const float4*)(Pbuf + c0 + i * 4);
    h[i * 4 + 0] = v.x; h[i * 4 + 1] = v.y;
    h[i * 4 + 2] = v.z; h[i * 4 + 3] = v.w;
  }

  const int tg0 = g * CLEN;
  const size_t row0 = (size_t)b * SEQ + tg0;
  const _Float16* dtp = dth + row0 * ED + d;
  const _Float16* xbp = xbh + row0 * ED + d;
  _Float16* rp = resh + row0 * ED + d;
  float x1, x2, x3;
  conv_init_h(xbp, tg0, x1, x2, x3);

  for (int t = 0; t < CLEN; ++t) {
    const float xt  = (float)xbp[(size_t)t * ED];
    const float dti = (float)dtp[(size_t)t * ED];
    float cv = cbd;
    cv = fmaf(wv.w, xt, cv);
    cv = fmaf(wv.z, x1, cv);
    cv = fmaf(wv.y, x2, cv);
    cv = fmaf(wv.x, x3, cv);
    const float ui = silu_f(cv);
    x3 = x2; x2 = x1; x1 = xt;

    const float4* bc = (const float4*)(dbc + (row0 + t) * 96 + DR);  // uniform
    float Bv[16], Cv[16];
    #pragma unroll
    for (int i = 0; i < 4; ++i) {
      const float4 v = bc[i];
      Bv[i * 4 + 0] = v.x; Bv[i * 4 + 1] = v.y;
      Bv[i * 4 + 2] = v.z; Bv[i * 4 + 3] = v.w;
      const float4 w = bc[4 + i];
      Cv[i * 4 + 0] = w.x; Cv[i * 4 + 1] = w.y;
      Cv[i * 4 + 2] = w.z; Cv[i * 4 + 3] = w.w;
    }
    const float dtu = dti * ui;
    float y = Dd * ui;
    #pragma unroll
    for (int n = 0; n < 16; ++n) {
      const float a = __expf(dti * Adn[n]);
      h[n] = fmaf(h[n], a, dtu * Bv[n]);
      y = fmaf(h[n], Cv[n], y);
    }
    const float sres = (float)rp[(size_t)t * ED];   // silu(res), read before write
    rp[(size_t)t * ED] = (_Float16)(y * sres);      // y_h in-place
  }
}

extern "C" void kernel_launch(void* const* d_in, const int* in_sizes, int n_in,
                              void* d_out, int out_size, void* d_ws, size_t ws_size,
                              hipStream_t stream) {
  (void)in_sizes; (void)n_in; (void)out_size; (void)ws_size;
  const float* x     = (const float*)d_in[0];
  const float* Win   = (const float*)d_in[1];
  const float* convw = (const float*)d_in[2];
  const float* convb = (const float*)d_in[3];
  const float* Wx    = (const float*)d_in[4];
  const float* Wdt   = (const float*)d_in[5];
  const float* bdt   = (const float*)d_in[6];
  const float* Alog  = (const float*)d_in[7];
  const float* Dp    = (const float*)d_in[8];
  const float* Wout  = (const float*)d_in[9];

  float* ws   = (float*)d_ws;
  _Float16* xbh  = (_Float16*)(ws + OFF_XBH);
  _Float16* resh = (_Float16*)(ws + OFF_RESH);
  float* Pbuf = ws + OFF_PS;                           // 4,194,304 f
  float* Sbuf = ws + OFF_PS + 4194304;                 // 4,194,304 f
  _Float16* dth = (_Float16*)(ws + OFF_DT);            // 8.4M halves
  float* dbc  = ws + OFF_DBC;
  float* part = ws + OFF_PART;
  _Float16* Woutt  = (_Float16*)(part + 3145728);      // 2M halves
  _Float16* Wxt    = (_Float16*)(part + 4194304);      // 192K halves
  _Float16* dbc64h = (_Float16*)(part + 4292608);      // 256K halves
  _Float16* Wdtt   = (_Float16*)(part + 4423680);      // 128K halves
  float* out  = (float*)d_out;

  _Float16* x_h  = (_Float16*)(ws + OFF_DT);           // staging (dead -> dth)
  _Float16* Wint = (_Float16*)(ws + OFF_DT + 2097152); // staging (dead -> dth)
  _Float16* u_h  = (_Float16*)(ws + OFF_DT + 4194304); // staging (dead after xproj)

  // 0) fused prep: cvt x + transpose-convert Win/Wout/Wx/Wdt
  prep_kernel<<<PREP_BLOCKS, 256, 0, stream>>>(
      x, x_h, Win, Wint, Wout, Woutt, Wx, Wxt, Wdt, Wdtt);
  // 1) in_proj: xbh fp16 + resh = (fp16)silu(res)
  hgemm<128, 2, 2, 2, 1, 64><<<dim3((2 * ED) / 128, NROWS / 128), 256, 0, stream>>>(
      x_h, DM, Wint, DM, nullptr, nullptr, xbh, resh, 0, 2 * ED, DM);
  // 2) u_h = (fp16)silu(causal_dwconv(xbh) + conv_b)
  conv_silu_kernel<<<(NROWS * ED) / 256, 256, 0, stream>>>(xbh, convw, convb, u_h);
  // 3) dbc = u @ x_proj_w  (MFMA, split-K=8 + reduce; reduce emits dbc64h fp16)
  hgemm<96, 4, 1, 0, 8, 64><<<dim3(1, NROWS / 128, 8), 256, 0, stream>>>(
      u_h, ED, Wxt, ED, nullptr, part, nullptr, nullptr, (size_t)NROWS * 96, 96, ED);
  xproj_reduce<<<(NROWS * 96) / 256, 256, 0, stream>>>(part, dbc, dbc64h);
  // 4) dth = (fp16)softplus(dbc64 @ dt_proj_w + b)  (MFMA K=64, single K-iter)
  hgemm<128, 2, 2, 3, 1, 64><<<dim3(ED / 128, NROWS / 128), 256, 0, stream>>>(
      dbc64h, DR, Wdtt, DR, bdt, nullptr, dth, nullptr, 0, ED, DR);
  // 5) chunked scan, channel-per-lane, conv recomputed inline from xbh
  scan2_summary<<<dim3(ED / 256, BATCH, NCHUNK), 256, 0, stream>>>(
      dth, xbh, convw, convb, dbc, Alog, Pbuf, Sbuf);
  scan2_compose<<<CSTATES / 256, 256, 0, stream>>>(Pbuf, Sbuf);
  scan2_apply<<<dim3(ED / 256, BATCH, NCHUNK), 256, 0, stream>>>(
      dth, xbh, convw, convb, dbc, Alog, Dp, Pbuf, resh);
  // 6) out = y_h @ out_proj_w  (MFMA)
  hgemm<64, 4, 1, 0, 1, 64><<<dim3(DM / 64, NROWS / 128), 256, 0, stream>>>(
      resh, ED, Woutt, ED, nullptr, out, nullptr, nullptr, 0, DM, ED);
}

// Round 7
// 340.935 us; speedup vs baseline: 4.5185x; 1.0301x over previous
//
#include <hip/hip_runtime.h>
#include <cstddef>
#include <cstdint>

// Problem constants
#define BATCH 2
#define SEQ   2048
#define DM    1024   // d_model
#define ED    2048   // d_inner
#define NS    16     // d_state
#define DR    64     // dt_rank
#define NROWS (BATCH*SEQ)  // 4096

// Chunked-scan parameters: SEQ = NCHUNK * CLEN
#define NCHUNK 32
#define CLEN   64
#define CSTATES (BATCH*ED*NS)   // 65536 independent recurrences

// ---------------------------------------------------------------------------
// workspace layout (float offsets), ~73.5 MB
// ---------------------------------------------------------------------------
#define OFF_XBH   ((size_t)0)          // 4,194,304 f (B,L,ED) fp16 conv input
#define OFF_RESH  ((size_t)4194304)    // 4,194,304 f (B,L,ED) fp16 silu(res); apply overwrites with y_h
#define OFF_PS    ((size_t)8388608)    // 4,194,304 f P (2,097,152) + S (2,097,152)
#define OFF_DT    ((size_t)12582912)   // 4,194,304 f dth (8.4M halves);
                                       //   staging x_h (2,097,152 f) + Wint (2,097,152 f) live here
                                       //   before dt_kernel overwrites (both dead after in_proj)
#define OFF_DBC   ((size_t)16777216)   //   393,216 f (B,L,96) fp32, atomicAdd target (prep zeroes)
#define OFF_WT    ((size_t)17170432)   // Woutt 1,048,576 f | Wxt 98,304 f | Wdtt 65,536 f

typedef _Float16 half8 __attribute__((ext_vector_type(8)));
typedef _Float16 half4 __attribute__((ext_vector_type(4)));
typedef float    floatx4 __attribute__((ext_vector_type(4)));

__device__ __forceinline__ float silu_f(float x) { return x / (1.f + __expf(-x)); }

__device__ __forceinline__ void gload_lds16(const _Float16* g, _Float16* l) {
  __builtin_amdgcn_global_load_lds(
      (const __attribute__((address_space(1))) void*)g,
      (__attribute__((address_space(3))) void*)l, 16, 0, 0);
}

// ---------------------------------------------------------------------------
// fp16 MFMA GEMM (in_proj / out_proj): C = A(MxK fp16 rm) @ Bt^T (Bt[n][k]).
// BM=128, BK=64, 256 threads (4 waves WGM x WGN), 16x16x32 MFMA.
// LDS [row][16B-chunk], XOR swizzle c_l = c_g ^ ((row>>1)&(CPR-1)): keeps
// global_load_lds lane order, frag ds_read_b128 = free 2-way bank alias.
// EPI 0: fp32 store. EPI 2: col<ED -> Ch=(fp16)v; col>=ED -> Ch2=(fp16)silu(v).
// ---------------------------------------------------------------------------
template<int BN, int WGM, int WGN, int EPI, int BK>
__global__ __launch_bounds__(256)
void hgemm(const _Float16* __restrict__ A, int lda,
           const _Float16* __restrict__ Bt, int ldb,
           float* __restrict__ C, _Float16* __restrict__ Ch,
           _Float16* __restrict__ Ch2, int N, int K) {
  constexpr int BM = 128;
  constexpr int FM = BM / 16 / WGM;
  constexpr int FN = BN / 16 / WGN;
  constexpr int CPR = BK / 8;
  __shared__ _Float16 sA[BM * BK];
  __shared__ _Float16 sB[BN * BK];
  const int tid = threadIdx.x;
  const int ln  = tid & 63;
  const int wid = tid >> 6;
  const int wm  = wid % WGM;
  const int wn  = wid / WGM;
  const int m0  = blockIdx.y * BM;
  const int n0  = blockIdx.x * BN;
  const int l15 = ln & 15;
  const int q   = ln >> 4;

  floatx4 acc[FM][FN];
  #pragma unroll
  for (int i = 0; i < FM; ++i)
    #pragma unroll
    for (int j = 0; j < FN; ++j)
      acc[i][j] = floatx4{0.f, 0.f, 0.f, 0.f};

  for (int k0 = 0; k0 < K; k0 += BK) {
    __syncthreads();
    #pragma unroll
    for (int s = 0; s < (BM * CPR) / 256; ++s) {
      const int i = s * 256 + tid;
      const int m = i / CPR;
      const int cg = (i & (CPR - 1)) ^ ((m >> 1) & (CPR - 1));
      gload_lds16(A + (size_t)(m0 + m) * lda + k0 + cg * 8, sA + i * 8);
    }
    #pragma unroll
    for (int s = 0; s < (BN * CPR) / 256; ++s) {
      const int i = s * 256 + tid;
      const int n = i / CPR;
      const int cg = (i & (CPR - 1)) ^ ((n >> 1) & (CPR - 1));
      gload_lds16(Bt + (size_t)(n0 + n) * ldb + k0 + cg * 8, sB + i * 8);
    }
    __syncthreads();

    #pragma unroll
    for (int h = 0; h < BK / 32; ++h) {
      half8 af[FM], bf[FN];
      #pragma unroll
      for (int fm = 0; fm < FM; ++fm) {
        const int mr = wm * FM * 16 + fm * 16 + l15;
        const int cl = (h * 4 + q) ^ ((mr >> 1) & (CPR - 1));
        af[fm] = *(const half8*)(sA + mr * BK + cl * 8);
      }
      #pragma unroll
      for (int fn = 0; fn < FN; ++fn) {
        const int nr = wn * FN * 16 + fn * 16 + l15;
        const int cl = (h * 4 + q) ^ ((nr >> 1) & (CPR - 1));
        bf[fn] = *(const half8*)(sB + nr * BK + cl * 8);
      }
      #pragma unroll
      for (int fm = 0; fm < FM; ++fm)
        #pragma unroll
        for (int fn = 0; fn < FN; ++fn)
          acc[fm][fn] = __builtin_amdgcn_mfma_f32_16x16x32_f16(
              af[fm], bf[fn], acc[fm][fn], 0, 0, 0);
    }
  }

  // C/D layout: col = lane&15, row = (lane>>4)*4 + reg  (m89/m91 verified)
  #pragma unroll
  for (int fm = 0; fm < FM; ++fm) {
    #pragma unroll
    for (int fn = 0; fn < FN; ++fn) {
      const int col = n0 + wn * FN * 16 + fn * 16 + l15;
      #pragma unroll
      for (int r = 0; r < 4; ++r) {
        const int row = m0 + wm * FM * 16 + fm * 16 + q * 4 + r;
        const float v = acc[fm][fn][r];
        if (EPI == 2) {
          if (col < ED) Ch[(size_t)row * ED + col] = (_Float16)v;
          else          Ch2[(size_t)row * ED + (col - ED)] = (_Float16)silu_f(v);
        } else {
          C[(size_t)row * N + col] = v;
        }
      }
    }
  }
}

// ---------------------------------------------------------------------------
// xproj with fused conv: dbc += silu(conv(xbh)+cb) @ Wxt^T, split-K=8 via
// atomicAdd. A-tile staged by computing u on the fly (ds_write path);
// B-tile (Wxt[n][k]) via global_load_lds. BM=128, BN=96, BK=64.
// grid (NROWS/128, 8).
// ---------------------------------------------------------------------------
__global__ __launch_bounds__(256)
void xproj_conv_kernel(const _Float16* __restrict__ xbh,
                       const float* __restrict__ convw,
                       const float* __restrict__ convb,
                       const _Float16* __restrict__ Wxt,
                       float* __restrict__ dbc) {
  constexpr int BM = 128, BN = 96, BK = 64, CPR = 8;
  __shared__ _Float16 sA[BM * BK];
  __shared__ _Float16 sB[BN * BK];
  const int tid = threadIdx.x;
  const int ln  = tid & 63;
  const int wid = tid >> 6;        // WGM=4, WGN=1
  const int m0  = blockIdx.x * BM;
  const int l15 = ln & 15;
  const int q   = ln >> 4;
  const int kbeg = blockIdx.y * (ED / 8);   // 256-wide K slice

  floatx4 acc[2][6];
  #pragma unroll
  for (int i = 0; i < 2; ++i)
    #pragma unroll
    for (int j = 0; j < 6; ++j) acc[i][j] = floatx4{0.f, 0.f, 0.f, 0.f};

  for (int k0 = kbeg; k0 < kbeg + ED / 8; k0 += BK) {
    __syncthreads();
    // A-tile: u[m0+m][k0+cg*8 .. +8] computed inline (conv+silu)
    #pragma unroll
    for (int s = 0; s < (BM * CPR) / 256; ++s) {
      const int i = s * 256 + tid;
      const int m = i / CPR;
      const int cg = (i & (CPR - 1)) ^ ((m >> 1) & (CPR - 1));
      const int r = m0 + m;
      const int t = r & (SEQ - 1);
      const int ch = k0 + cg * 8;
      const _Float16* xp = xbh + (size_t)r * ED + ch;
      const half8 v0 = *(const half8*)(xp);
      half8 v1 = {}, v2 = {}, v3 = {};
      if (t >= 1) v1 = *(const half8*)(xp - ED);
      if (t >= 2) v2 = *(const half8*)(xp - 2 * ED);
      if (t >= 3) v3 = *(const half8*)(xp - 3 * ED);
      half8 o;
      #pragma unroll
      for (int j = 0; j < 8; ++j) {
        const float4 wv = ((const float4*)convw)[ch + j];
        float a = convb[ch + j];
        a = fmaf(wv.w, (float)v0[j], a);
        a = fmaf(wv.z, (float)v1[j], a);
        a = fmaf(wv.y, (float)v2[j], a);
        a = fmaf(wv.x, (float)v3[j], a);
        o[j] = (_Float16)silu_f(a);
      }
      *(half8*)(sA + i * 8) = o;
    }
    // B-tile: Wxt[n][k], 96*8 = 768 slots
    #pragma unroll
    for (int s = 0; s < 3; ++s) {
      const int i = s * 256 + tid;
      const int n = i / CPR;
      const int cg = (i & (CPR - 1)) ^ ((n >> 1) & (CPR - 1));
      gload_lds16(Wxt + (size_t)n * ED + k0 + cg * 8, sB + i * 8);
    }
    __syncthreads();

    #pragma unroll
    for (int h = 0; h < 2; ++h) {
      half8 af[2], bf[6];
      #pragma unroll
      for (int fm = 0; fm < 2; ++fm) {
        const int mr = wid * 32 + fm * 16 + l15;
        const int cl = (h * 4 + q) ^ ((mr >> 1) & (CPR - 1));
        af[fm] = *(const half8*)(sA + mr * BK + cl * 8);
      }
      #pragma unroll
      for (int fn = 0; fn < 6; ++fn) {
        const int nr = fn * 16 + l15;
        const int cl = (h * 4 + q) ^ ((nr >> 1) & (CPR - 1));
        bf[fn] = *(const half8*)(sB + nr * BK + cl * 8);
      }
      #pragma unroll
      for (int fm = 0; fm < 2; ++fm)
        #pragma unroll
        for (int fn = 0; fn < 6; ++fn)
          acc[fm][fn] = __builtin_amdgcn_mfma_f32_16x16x32_f16(
              af[fm], bf[fn], acc[fm][fn], 0, 0, 0);
    }
  }

  #pragma unroll
  for (int fm = 0; fm < 2; ++fm) {
    #pragma unroll
    for (int fn = 0; fn < 6; ++fn) {
      const int col = fn * 16 + l15;
      #pragma unroll
      for (int r = 0; r < 4; ++r) {
        const int row = m0 + wid * 32 + fm * 16 + q * 4 + r;
        unsafeAtomicAdd(&dbc[(size_t)row * 96 + col], acc[fm][fn][r]);
      }
    }
  }
}

// ---------------------------------------------------------------------------
// dt_proj: dth = (fp16)softplus(dbc[:, :64] @ Wdtt^T + bdt). K=64 single
// K-iter; A staged from dbc fp32 with convert (ds_write); B via
// global_load_lds. BM=128, BN=128, WGM=2, WGN=2. grid (ED/128, NROWS/128).
// ---------------------------------------------------------------------------
__global__ __launch_bounds__(256)
void dt_kernel(const float* __restrict__ dbc, const _Float16* __restrict__ Wdtt,
               const float* __restrict__ bdt, _Float16* __restrict__ dth) {
  constexpr int BM = 128, BN = 128, BK = 64, CPR = 8;
  __shared__ _Float16 sA[BM * BK];
  __shared__ _Float16 sB[BN * BK];
  const int tid = threadIdx.x;
  const int ln  = tid & 63;
  const int wid = tid >> 6;
  const int wm  = wid & 1;         // WGM=2
  const int wn  = wid >> 1;        // WGN=2
  const int m0  = blockIdx.y * BM;
  const int n0  = blockIdx.x * BN;
  const int l15 = ln & 15;
  const int q   = ln >> 4;

  // A-tile: rows m0..m0+127, cols 0..63 of dbc (row stride 96), fp32 -> fp16
  #pragma unroll
  for (int s = 0; s < 4; ++s) {
    const int i = s * 256 + tid;
    const int m = i / CPR;
    const int cg = (i & (CPR - 1)) ^ ((m >> 1) & (CPR - 1));
    const float* p = dbc + (size_t)(m0 + m) * 96 + cg * 8;
    const float4 a = *(const float4*)(p);
    const float4 b = *(const float4*)(p + 4);
    half8 o;
    o[0] = (_Float16)a.x; o[1] = (_Float16)a.y; o[2] = (_Float16)a.z; o[3] = (_Float16)a.w;
    o[4] = (_Float16)b.x; o[5] = (_Float16)b.y; o[6] = (_Float16)b.z; o[7] = (_Float16)b.w;
    *(half8*)(sA + i * 8) = o;
  }
  #pragma unroll
  for (int s = 0; s < 4; ++s) {
    const int i = s * 256 + tid;
    const int n = i / CPR;
    const int cg = (i & (CPR - 1)) ^ ((n >> 1) & (CPR - 1));
    gload_lds16(Wdtt + (size_t)(n0 + n) * DR + cg * 8, sB + i * 8);
  }
  __syncthreads();

  floatx4 acc[4][4];
  #pragma unroll
  for (int i = 0; i < 4; ++i)
    #pragma unroll
    for (int j = 0; j < 4; ++j) acc[i][j] = floatx4{0.f, 0.f, 0.f, 0.f};

  #pragma unroll
  for (int h = 0; h < 2; ++h) {
    half8 af[4], bf[4];
    #pragma unroll
    for (int fm = 0; fm < 4; ++fm) {
      const int mr = wm * 64 + fm * 16 + l15;
      const int cl = (h * 4 + q) ^ ((mr >> 1) & (CPR - 1));
      af[fm] = *(const half8*)(sA + mr * BK + cl * 8);
    }
    #pragma unroll
    for (int fn = 0; fn < 4; ++fn) {
      const int nr = wn * 64 + fn * 16 + l15;
      const int cl = (h * 4 + q) ^ ((nr >> 1) & (CPR - 1));
      bf[fn] = *(const half8*)(sB + nr * BK + cl * 8);
    }
    #pragma unroll
    for (int fm = 0; fm < 4; ++fm)
      #pragma unroll
      for (int fn = 0; fn < 4; ++fn)
        acc[fm][fn] = __builtin_amdgcn_mfma_f32_16x16x32_f16(
            af[fm], bf[fn], acc[fm][fn], 0, 0, 0);
  }

  #pragma unroll
  for (int fm = 0; fm < 4; ++fm) {
    #pragma unroll
    for (int fn = 0; fn < 4; ++fn) {
      const int col = n0 + wn * 64 + fn * 16 + l15;
      #pragma unroll
      for (int r = 0; r < 4; ++r) {
        const int row = m0 + wm * 64 + fm * 16 + q * 4 + r;
        float v = acc[fm][fn][r] + bdt[col];
        v = fmaxf(v, 0.f) + log1pf(__expf(-fabsf(v)));  // stable softplus
        dth[(size_t)row * ED + col] = (_Float16)v;
      }
    }
  }
}

// ---------------------------------------------------------------------------
// Fused prep: x cvt + 4 transpose-converts + zero dbc, by block range.
// ---------------------------------------------------------------------------
__device__ __forceinline__ void transpose_tile(const float* __restrict__ src,
                                               _Float16* __restrict__ dst,
                                               int R, int C, int bx, int by,
                                               int tid) {
  __shared__ float t[32][33];
  const int tx = tid & 31, ty = tid >> 5;
  const int c0 = bx * 32, r0 = by * 32;
  #pragma unroll
  for (int s = 0; s < 4; ++s)
    t[ty + s * 8][tx] = src[(size_t)(r0 + ty + s * 8) * C + c0 + tx];
  __syncthreads();
  #pragma unroll
  for (int s = 0; s < 4; ++s)
    dst[(size_t)(c0 + ty + s * 8) * R + r0 + tx] = (_Float16)t[tx][ty + s * 8];
}

// [0,4096) cvt x | [4096,8192) Win^T | [8192,10240) Wout^T |
// [10240,10432) Wx^T | [10432,10560) Wdt^T | [10560,10944) zero dbc
#define PREP_BLOCKS 10944
__global__ __launch_bounds__(256)
void prep_kernel(const float* __restrict__ x, _Float16* __restrict__ x_h,
                 const float* __restrict__ Win, _Float16* __restrict__ Wint,
                 const float* __restrict__ Wout, _Float16* __restrict__ Woutt,
                 const float* __restrict__ Wx, _Float16* __restrict__ Wxt,
                 const float* __restrict__ Wdt, _Float16* __restrict__ Wdtt,
                 float* __restrict__ dbc) {
  const int bid = blockIdx.x, tid = threadIdx.x;
  if (bid < 4096) {
    const int i = bid * 1024 + tid * 4;
    const float4 v = *(const float4*)(x + i);
    half4 o;
    o[0] = (_Float16)v.x; o[1] = (_Float16)v.y;
    o[2] = (_Float16)v.z; o[3] = (_Float16)v.w;
    *(half4*)(x_h + i) = o;
  } else if (bid < 8192) {
    const int t = bid - 4096;            // Win: 1024 x 4096 -> 4096 x 1024
    transpose_tile(Win, Wint, DM, 2 * ED, t & 127, t >> 7, tid);
  } else if (bid < 10240) {
    const int t = bid - 8192;            // Wout: 2048 x 1024 -> 1024 x 2048
    transpose_tile(Wout, Woutt, ED, DM, t & 31, t >> 5, tid);
  } else if (bid < 10432) {
    const int t = bid - 10240;           // Wx: 2048 x 96 -> 96 x 2048
    transpose_tile(Wx, Wxt, ED, 96, t % 3, t / 3, tid);
  } else if (bid < 10560) {
    const int t = bid - 10432;           // Wdt: 64 x 2048 -> 2048 x 64
    transpose_tile(Wdt, Wdtt, DR, ED, t & 63, t >> 6, tid);
  } else {
    const int i = (bid - 10560) * 1024 + tid * 4;
    *(float4*)(dbc + i) = float4{0.f, 0.f, 0.f, 0.f};
  }
}

// ---------------------------------------------------------------------------
// Channel-per-lane chunked scan with inline conv recompute (fp16 xb/dt in,
// fp32 state). Thread = (d, b, chunk g); 16 states in registers.
// ---------------------------------------------------------------------------
__device__ __forceinline__ void conv_init_h(const _Float16* xbp, int tg0,
                                            float& x1, float& x2, float& x3) {
  x1 = (tg0 >= 1) ? (float)xbp[-(int)ED] : 0.f;
  x2 = (tg0 >= 2) ? (float)xbp[-2 * (int)ED] : 0.f;
  x3 = (tg0 >= 3) ? (float)xbp[-3 * (int)ED] : 0.f;
}

__global__ __launch_bounds__(256)
void scan2_summary(const _Float16* __restrict__ dth, const _Float16* __restrict__ xbh,
                   const float* __restrict__ convw, const float* __restrict__ convb,
                   const float* __restrict__ dbc, const float* __restrict__ A_log,
                   float* __restrict__ Pbuf, float* __restrict__ Sbuf) {
  const int d = blockIdx.x * 256 + threadIdx.x;   // grid.x = ED/256
  const int b = blockIdx.y;
  const int g = blockIdx.z;

  float Adn[16];
  {
    const float4* al = (const float4*)(A_log + (size_t)d * NS);
    #pragma unroll
    for (int i = 0; i < 4; ++i) {
      const float4 v = al[i];
      Adn[i * 4 + 0] = -__expf(v.x); Adn[i * 4 + 1] = -__expf(v.y);
      Adn[i * 4 + 2] = -__expf(v.z); Adn[i * 4 + 3] = -__expf(v.w);
    }
  }
  const float4 wv = ((const float4*)convw)[d];
  const float cbd = convb[d];

  float P[16], S[16];
  #pragma unroll
  for (int n = 0; n < 16; ++n) { P[n] = 1.f; S[n] = 0.f; }

  const int tg0 = g * CLEN;
  const size_t row0 = (size_t)b * SEQ + tg0;
  const _Float16* dtp = dth + row0 * ED + d;
  const _Float16* xbp = xbh + row0 * ED + d;
  float x1, x2, x3;
  conv_init_h(xbp, tg0, x1, x2, x3);

  for (int t = 0; t < CLEN; ++t) {
    const float xt  = (float)xbp[(size_t)t * ED];
    const float dti = (float)dtp[(size_t)t * ED];
    float cv = cbd;
    cv = fmaf(wv.w, xt, cv);
    cv = fmaf(wv.z, x1, cv);
    cv = fmaf(wv.y, x2, cv);
    cv = fmaf(wv.x, x3, cv);
    const float ui = silu_f(cv);
    x3 = x2; x2 = x1; x1 = xt;

    const float4* bc = (const float4*)(dbc + (row0 + t) * 96 + DR);  // uniform
    float Bv[16];
    #pragma unroll
    for (int i = 0; i < 4; ++i) {
      const float4 v = bc[i];
      Bv[i * 4 + 0] = v.x; Bv[i * 4 + 1] = v.y;
      Bv[i * 4 + 2] = v.z; Bv[i * 4 + 3] = v.w;
    }
    const float dtu = dti * ui;
    #pragma unroll
    for (int n = 0; n < 16; ++n) {
      const float a = __expf(dti * Adn[n]);
      S[n] = fmaf(S[n], a, dtu * Bv[n]);
      P[n] *= a;
    }
  }
  const size_t c0 = (size_t)g * CSTATES + ((size_t)(b * ED + d)) * NS;
  #pragma unroll
  for (int i = 0; i < 4; ++i) {
    *(float4*)(Pbuf + c0 + i * 4) = float4{P[i*4], P[i*4+1], P[i*4+2], P[i*4+3]};
    *(float4*)(Sbuf + c0 + i * 4) = float4{S[i*4], S[i*4+1], S[i*4+2], S[i*4+3]};
  }
}

// Compose chunk summaries -> each chunk's ENTRY state h0 (in-place over Pbuf).
__global__ __launch_bounds__(256)
void scan2_compose(float* __restrict__ Pbuf, const float* __restrict__ Sbuf) {
  const unsigned c = blockIdx.x * 256 + threadIdx.x;  // < CSTATES
  float h = 0.f;
  for (int g = 0; g < NCHUNK; ++g) {
    const size_t idx = (size_t)g * CSTATES + c;
    const float p = Pbuf[idx], s = Sbuf[idx];
    Pbuf[idx] = h;
    h = fmaf(p, h, s);
  }
}

// Final pass: recurrence from h0; fused gate y_h = (fp16)(y * silu_res),
// written IN-PLACE over resh (same element, same thread, read-before-write).
__global__ __launch_bounds__(256)
void scan2_apply(const _Float16* __restrict__ dth, const _Float16* __restrict__ xbh,
                 const float* __restrict__ convw, const float* __restrict__ convb,
                 const float* __restrict__ dbc, const float* __restrict__ A_log,
                 const float* __restrict__ Dp, const float* __restrict__ Pbuf,
                 _Float16* __restrict__ resh) {
  const int d = blockIdx.x * 256 + threadIdx.x;
  const int b = blockIdx.y;
  const int g = blockIdx.z;

  float Adn[16];
  {
    const float4* al = (const float4*)(A_log + (size_t)d * NS);
    #pragma unroll
    for (int i = 0; i < 4; ++i) {
      const float4 v = al[i];
      Adn[i * 4 + 0] = -__expf(v.x); Adn[i * 4 + 1] = -__expf(v.y);
      Adn[i * 4 + 2] = -__expf(v.z); Adn[i * 4 + 3] = -__expf(v.w);
    }
  }
  const float4 wv = ((const float4*)convw)[d];
  const float cbd = convb[d];
  const float Dd = Dp[d];

  float h[16];
  const size_t c0 = (size_t)g * CSTATES + ((size_t)(b * ED + d)) * NS;
  #pragma unroll
  for (int i = 0; i < 4; ++i) {
    const float4 v = *(const float4*)(Pbuf + c0 + i * 4);
    h[i * 4 + 0] = v.x; h[i * 4 + 1] = v.y;
    h[i * 4 + 2] = v.z; h[i * 4 + 3] = v.w;
  }

  const int tg0 = g * CLEN;
  const size_t row0 = (size_t)b * SEQ + tg0;
  const _Float16* dtp = dth + row0 * ED + d;
  const _Float16* xbp = xbh + row0 * ED + d;
  _Float16* rp = resh + row0 * ED + d;
  float x1, x2, x3;
  conv_init_h(xbp, tg0, x1, x2, x3);

  for (int t = 0; t < CLEN; ++t) {
    const float xt  = (float)xbp[(size_t)t * ED];
    const float dti = (float)dtp[(size_t)t * ED];
    float cv = cbd;
    cv = fmaf(wv.w, xt, cv);
    cv = fmaf(wv.z, x1, cv);
    cv = fmaf(wv.y, x2, cv);
    cv = fmaf(wv.x, x3, cv);
    const float ui = silu_f(cv);
    x3 = x2; x2 = x1; x1 = xt;

    const float4* bc = (const float4*)(dbc + (row0 + t) * 96 + DR);  // uniform
    float Bv[16], Cv[16];
    #pragma unroll
    for (int i = 0; i < 4; ++i) {
      const float4 v = bc[i];
      Bv[i * 4 + 0] = v.x; Bv[i * 4 + 1] = v.y;
      Bv[i * 4 + 2] = v.z; Bv[i * 4 + 3] = v.w;
      const float4 w = bc[4 + i];
      Cv[i * 4 + 0] = w.x; Cv[i * 4 + 1] = w.y;
      Cv[i * 4 + 2] = w.z; Cv[i * 4 + 3] = w.w;
    }
    const float dtu = dti * ui;
    float y = Dd * ui;
    #pragma unroll
    for (int n = 0; n < 16; ++n) {
      const float a = __expf(dti * Adn[n]);
      h[n] = fmaf(h[n], a, dtu * Bv[n]);
      y = fmaf(h[n], Cv[n], y);
    }
    const float sres = (float)rp[(size_t)t * ED];   // silu(res), read before write
    rp[(size_t)t * ED] = (_Float16)(y * sres);      // y_h in-place
  }
}

extern "C" void kernel_launch(void* const* d_in, const int* in_sizes, int n_in,
                              void* d_out, int out_size, void* d_ws, size_t ws_size,
                              hipStream_t stream) {
  (void)in_sizes; (void)n_in; (void)out_size; (void)ws_size;
  const float* x     = (const float*)d_in[0];
  const float* Win   = (const float*)d_in[1];
  const float* convw = (const float*)d_in[2];
  const float* convb = (const float*)d_in[3];
  const float* Wx    = (const float*)d_in[4];
  const float* Wdt   = (const float*)d_in[5];
  const float* bdt   = (const float*)d_in[6];
  const float* Alog  = (const float*)d_in[7];
  const float* Dp    = (const float*)d_in[8];
  const float* Wout  = (const float*)d_in[9];

  float* ws   = (float*)d_ws;
  _Float16* xbh  = (_Float16*)(ws + OFF_XBH);
  _Float16* resh = (_Float16*)(ws + OFF_RESH);
  float* Pbuf = ws + OFF_PS;                           // 2,097,152 f
  float* Sbuf = ws + OFF_PS + 2097152;                 // 2,097,152 f
  _Float16* dth = (_Float16*)(ws + OFF_DT);            // 8.4M halves
  float* dbc  = ws + OFF_DBC;
  _Float16* Woutt = (_Float16*)(ws + OFF_WT);          // 2M halves
  _Float16* Wxt   = (_Float16*)(ws + OFF_WT + 1048576);
  _Float16* Wdtt  = (_Float16*)(ws + OFF_WT + 1146880);
  float* out  = (float*)d_out;

  _Float16* x_h  = (_Float16*)(ws + OFF_DT);           // staging (dead -> dth)
  _Float16* Wint = (_Float16*)(ws + OFF_DT + 2097152); // staging (dead -> dth)

  // 0) fused prep: cvt x + transpose Win/Wout/Wx/Wdt + zero dbc
  prep_kernel<<<PREP_BLOCKS, 256, 0, stream>>>(
      x, x_h, Win, Wint, Wout, Woutt, Wx, Wxt, Wdt, Wdtt, dbc);
  // 1) in_proj: xbh fp16 + resh = (fp16)silu(res)
  hgemm<128, 2, 2, 2, 64><<<dim3((2 * ED) / 128, NROWS / 128), 256, 0, stream>>>(
      x_h, DM, Wint, DM, nullptr, xbh, resh, 2 * ED, DM);
  // 2) dbc += silu(conv(xbh)) @ Wx  (fused conv staging, split-K=8 atomics)
  xproj_conv_kernel<<<dim3(NROWS / 128, 8), 256, 0, stream>>>(
      xbh, convw, convb, Wxt, dbc);
  // 3) dth = (fp16)softplus(dbc[:,:64] @ Wdt + b)  (fused fp32->fp16 staging)
  dt_kernel<<<dim3(ED / 128, NROWS / 128), 256, 0, stream>>>(
      dbc, Wdtt, bdt, dth);
  // 4) chunked scan, channel-per-lane, conv recomputed inline from xbh
  scan2_summary<<<dim3(ED / 256, BATCH, NCHUNK), 256, 0, stream>>>(
      dth, xbh, convw, convb, dbc, Alog, Pbuf, Sbuf);
  scan2_compose<<<CSTATES / 256, 256, 0, stream>>>(Pbuf, Sbuf);
  scan2_apply<<<dim3(ED / 256, BATCH, NCHUNK), 256, 0, stream>>>(
      dth, xbh, convw, convb, dbc, Alog, Dp, Pbuf, resh);
  // 5) out = y_h @ out_proj_w
  hgemm<64, 4, 1, 0, 64><<<dim3(DM / 64, NROWS / 128), 256, 0, stream>>>(
      resh, ED, Woutt, ED, out, nullptr, nullptr, DM, ED);
}